// Round 2
// baseline (457.452 us; speedup 1.0000x reference)
//
#include <hip/hip_runtime.h>
#include <stdint.h>

#define D_ 1024
#define S_ 2048
#define B_ 8
#define LDH 40   // LDS row stride in halves (80B): +16B pad -> 2-way max bank conflict
#define KT 256   // key tile in attention

typedef _Float16 h16;
typedef _Float16 f16x8 __attribute__((ext_vector_type(8)));
typedef _Float16 f16x4 __attribute__((ext_vector_type(4)));
typedef float    f32x4 __attribute__((ext_vector_type(4)));

#define MFMA16(a, b, c) __builtin_amdgcn_mfma_f32_16x16x32_f16(a, b, c, 0, 0, 0)

// ---------------- kernel 1: u[e] = Wv[e,:]·Wo ; u[D] = bv·Wo ----------------
__global__ void k_u(const float* __restrict__ Wv, const float* __restrict__ Wo,
                    const float* __restrict__ bv, float* __restrict__ u) {
  int e = blockIdx.x * 256 + threadIdx.x;
  if (e < D_) {
    const float4* row = (const float4*)(Wv + (size_t)e * D_);
    const float4* wo4 = (const float4*)Wo;
    float s = 0.f;
    #pragma unroll 4
    for (int j = 0; j < D_ / 4; ++j) {
      float4 a = row[j], b = wo4[j];
      s += a.x * b.x + a.y * b.y + a.z * b.z + a.w * b.w;
    }
    u[e] = s;
  }
  if (blockIdx.x == 0 && threadIdx.x == 0) {
    float s = 0.f;
    for (int d = 0; d < D_; ++d) s += bv[d] * Wo[d];
    u[D_] = s;
  }
}

// ------------- kernel 2: Wt[n][k] = (n<D ? Wq : Wk)[k][n]  (fp16) -----------
__global__ void k_wt(const float* __restrict__ Wq, const float* __restrict__ Wk,
                     h16* __restrict__ Wt) {
  __shared__ float t[32][33];
  int n0 = blockIdx.x * 32;
  int k0 = blockIdx.y * 32;
  const float* src = (n0 < D_) ? Wq : Wk;
  int nn = n0 & (D_ - 1);
  int tx = threadIdx.x, ty = threadIdx.y;
  for (int i = ty; i < 32; i += 8)
    t[i][tx] = src[(size_t)(k0 + i) * D_ + nn + tx];
  __syncthreads();
  for (int i = ty; i < 32; i += 8)
    Wt[(size_t)(n0 + i) * D_ + k0 + tx] = (h16)t[tx][i];
}

// -------- kernel 3: xh = fp16(x);  w[r] = x[r,:]·u + u[D]  (one wave/row) ---
__global__ void k_xw(const float* __restrict__ x, const float* __restrict__ u,
                     h16* __restrict__ xh, float* __restrict__ w) {
  int row = blockIdx.x * 4 + (threadIdx.x >> 6);
  int lane = threadIdx.x & 63;
  const float4* xr = (const float4*)(x + (size_t)row * D_);
  const float4* u4 = (const float4*)u;
  h16* xo = xh + (size_t)row * D_;
  float s = 0.f;
  #pragma unroll
  for (int j = 0; j < 4; ++j) {
    int c = j * 64 + lane;
    float4 a = xr[c];
    float4 b = u4[c];
    s += a.x * b.x + a.y * b.y + a.z * b.z + a.w * b.w;
    f16x4 o;
    o[0] = (h16)a.x; o[1] = (h16)a.y; o[2] = (h16)a.z; o[3] = (h16)a.w;
    *(f16x4*)(xo + c * 4) = o;
  }
  #pragma unroll
  for (int off = 32; off; off >>= 1) s += __shfl_xor(s, off, 64);
  if (lane == 0) w[row] = s + u[D_];
}

// ------ kernel 4: qkh[16384][2048] = xh·[Wq|Wk] + [bq|bk]   (fp16 out) ------
__global__ __launch_bounds__(256, 2) void k_proj(
    const h16* __restrict__ xh, const h16* __restrict__ Wt,
    const float* __restrict__ bq_, const float* __restrict__ bk_,
    h16* __restrict__ qkh) {
  __shared__ alignas(16) h16 As[128 * LDH];
  __shared__ alignas(16) h16 Bs[128 * LDH];
  int tid = threadIdx.x;
  int w = tid >> 6, lane = tid & 63;
  int wr = w >> 1, wc = w & 1;
  int g = lane >> 4, l15 = lane & 15;
  int m0 = blockIdx.y * 128, n0 = blockIdx.x * 128;

  int sr[2], sc[2];
  #pragma unroll
  for (int j = 0; j < 2; ++j) { int s = tid + j * 256; sr[j] = s >> 2; sc[j] = (s & 3) * 8; }

  f16x8 ra[2], rb[2];
  #pragma unroll
  for (int j = 0; j < 2; ++j) {
    ra[j] = *(const f16x8*)(xh + (size_t)(m0 + sr[j]) * D_ + sc[j]);
    rb[j] = *(const f16x8*)(Wt + (size_t)(n0 + sr[j]) * D_ + sc[j]);
  }

  f32x4 acc[4][4] = {};

  for (int k0 = 0; k0 < D_; k0 += 32) {
    __syncthreads();
    #pragma unroll
    for (int j = 0; j < 2; ++j) {
      *(f16x8*)(As + sr[j] * LDH + sc[j]) = ra[j];
      *(f16x8*)(Bs + sr[j] * LDH + sc[j]) = rb[j];
    }
    __syncthreads();
    int k1 = k0 + 32;
    if (k1 < D_) {
      #pragma unroll
      for (int j = 0; j < 2; ++j) {
        ra[j] = *(const f16x8*)(xh + (size_t)(m0 + sr[j]) * D_ + k1 + sc[j]);
        rb[j] = *(const f16x8*)(Wt + (size_t)(n0 + sr[j]) * D_ + k1 + sc[j]);
      }
    }
    f16x8 af[4], bf[4];
    #pragma unroll
    for (int i = 0; i < 4; ++i) {
      af[i] = *(const f16x8*)(As + (wr * 64 + i * 16 + l15) * LDH + g * 8);
      bf[i] = *(const f16x8*)(Bs + (wc * 64 + i * 16 + l15) * LDH + g * 8);
    }
    #pragma unroll
    for (int mi = 0; mi < 4; ++mi)
      #pragma unroll
      for (int ni = 0; ni < 4; ++ni)
        acc[mi][ni] = MFMA16(af[mi], bf[ni], acc[mi][ni]);
  }

  #pragma unroll
  for (int ni = 0; ni < 4; ++ni) {
    int n = n0 + wc * 64 + ni * 16 + l15;
    float bias = (n < D_) ? bq_[n] : bk_[n - D_];
    #pragma unroll
    for (int mi = 0; mi < 4; ++mi) {
      #pragma unroll
      for (int r = 0; r < 4; ++r) {
        int m = m0 + wr * 64 + mi * 16 + g * 4 + r;
        qkh[(size_t)m * (2 * D_) + n] = (h16)(acc[mi][ni][r] + bias);
      }
    }
  }
}

// -- kernel 5: out[b,s] = (Σ_t e^{S_st-m} w[b,t]) / (Σ_t e^{S_st-m}) + bo ----
__global__ __launch_bounds__(256, 1) void k_attn(
    const h16* __restrict__ qkh, const float* __restrict__ wv,
    const float* __restrict__ bo, float* __restrict__ out) {
  __shared__ alignas(16) h16 Qs[64 * LDH];
  __shared__ alignas(16) h16 Ks[256 * LDH];
  __shared__ float sm[3][4][64];
  int tid = threadIdx.x;
  int w = tid >> 6, lane = tid & 63;
  int g = lane >> 4, l15 = lane & 15;
  int b = blockIdx.x & 7;               // batch -> XCD affinity
  int q0 = (blockIdx.x >> 3) * 64;
  size_t rbase = (size_t)b * S_;

  int qr = tid >> 2, qc = (tid & 3) * 8;
  int kr[4], kc[4];
  #pragma unroll
  for (int j = 0; j < 4; ++j) { int s = tid + j * 256; kr[j] = s >> 2; kc[j] = (s & 3) * 8; }

  float mrun[4][4], num[4][4], den[4][4];
  #pragma unroll
  for (int mi = 0; mi < 4; ++mi)
    #pragma unroll
    for (int r = 0; r < 4; ++r) { mrun[mi][r] = -1e30f; num[mi][r] = 0.f; den[mi][r] = 0.f; }

  f16x8 rq, rk[4];
  rq = *(const f16x8*)(qkh + (rbase + q0 + qr) * (2 * D_) + qc);
  #pragma unroll
  for (int j = 0; j < 4; ++j)
    rk[j] = *(const f16x8*)(qkh + (rbase + kr[j]) * (2 * D_) + D_ + kc[j]);

  for (int tt = 0; tt < S_ / KT; ++tt) {
    f32x4 acc[4][4] = {};
    for (int k0 = 0; k0 < D_; k0 += 32) {
      __syncthreads();
      *(f16x8*)(Qs + qr * LDH + qc) = rq;
      #pragma unroll
      for (int j = 0; j < 4; ++j) *(f16x8*)(Ks + kr[j] * LDH + kc[j]) = rk[j];
      __syncthreads();
      int k1 = k0 + 32;
      int nt = tt;
      if (k1 >= D_) { k1 = 0; nt = tt + 1; }
      if (nt < S_ / KT) {
        rq = *(const f16x8*)(qkh + (rbase + q0 + qr) * (2 * D_) + k1 + qc);
        #pragma unroll
        for (int j = 0; j < 4; ++j)
          rk[j] = *(const f16x8*)(qkh + (rbase + nt * KT + kr[j]) * (2 * D_) + D_ + k1 + kc[j]);
      }
      f16x8 qf[4], kf[4];
      #pragma unroll
      for (int i = 0; i < 4; ++i) {
        qf[i] = *(const f16x8*)(Qs + (i * 16 + l15) * LDH + g * 8);
        kf[i] = *(const f16x8*)(Ks + (w * 64 + i * 16 + l15) * LDH + g * 8);
      }
      #pragma unroll
      for (int mi = 0; mi < 4; ++mi)
        #pragma unroll
        for (int ni = 0; ni < 4; ++ni)
          acc[mi][ni] = MFMA16(qf[mi], kf[ni], acc[mi][ni]);
    }
    // online softmax + fused Σp·w (t = tt*KT + w*64 + ni*16 + l15)
    float wvv[4];
    #pragma unroll
    for (int ni = 0; ni < 4; ++ni)
      wvv[ni] = wv[rbase + tt * KT + w * 64 + ni * 16 + l15];
    #pragma unroll
    for (int mi = 0; mi < 4; ++mi) {
      #pragma unroll
      for (int r = 0; r < 4; ++r) {
        float v = fmaxf(fmaxf(acc[mi][0][r], acc[mi][1][r]),
                        fmaxf(acc[mi][2][r], acc[mi][3][r]));
        #pragma unroll
        for (int off = 1; off < 16; off <<= 1) v = fmaxf(v, __shfl_xor(v, off, 64));
        float mn = fmaxf(mrun[mi][r], v);
        float scl = __expf(mrun[mi][r] - mn);
        float pn = 0.f, pd = 0.f;
        #pragma unroll
        for (int ni = 0; ni < 4; ++ni) {
          float p = __expf(acc[mi][ni][r] - mn);
          pn += p * wvv[ni];
          pd += p;
        }
        num[mi][r] = num[mi][r] * scl + pn;
        den[mi][r] = den[mi][r] * scl + pd;
        mrun[mi][r] = mn;
      }
    }
  }
  // reduce partial num/den across the 16 t-lanes
  #pragma unroll
  for (int mi = 0; mi < 4; ++mi)
    #pragma unroll
    for (int r = 0; r < 4; ++r) {
      #pragma unroll
      for (int off = 1; off < 16; off <<= 1) {
        num[mi][r] += __shfl_xor(num[mi][r], off, 64);
        den[mi][r] += __shfl_xor(den[mi][r], off, 64);
      }
    }
  if (l15 == 0) {
    #pragma unroll
    for (int mi = 0; mi < 4; ++mi)
      #pragma unroll
      for (int r = 0; r < 4; ++r) {
        int row = mi * 16 + g * 4 + r;
        sm[0][w][row] = mrun[mi][r];
        sm[1][w][row] = num[mi][r];
        sm[2][w][row] = den[mi][r];
      }
  }
  __syncthreads();
  if (tid < 64) {
    float M = sm[0][0][tid];
    #pragma unroll
    for (int j = 1; j < 4; ++j) M = fmaxf(M, sm[0][j][tid]);
    float N = 0.f, Dn = 0.f;
    #pragma unroll
    for (int j = 0; j < 4; ++j) {
      float e = __expf(sm[0][j][tid] - M);
      N += sm[1][j][tid] * e;
      Dn += sm[2][j][tid] * e;
    }
    out[rbase + q0 + tid] = N / Dn + bo[0];
  }
}

extern "C" void kernel_launch(void* const* d_in, const int* in_sizes, int n_in,
                              void* d_out, int out_size, void* d_ws, size_t ws_size,
                              hipStream_t stream) {
  const float* x  = (const float*)d_in[0];
  const float* Wq = (const float*)d_in[1];
  const float* bq = (const float*)d_in[2];
  const float* Wk = (const float*)d_in[3];
  const float* bk = (const float*)d_in[4];
  const float* Wv = (const float*)d_in[5];
  const float* bv = (const float*)d_in[6];
  const float* Wo = (const float*)d_in[7];
  const float* bo = (const float*)d_in[8];
  float* out = (float*)d_out;

  char* ws = (char*)d_ws;
  h16*   xh  = (h16*)ws;                                    // 32 MB
  h16*   Wt  = (h16*)(ws + (size_t)32 * 1024 * 1024);       // 4 MB
  h16*   qkh = (h16*)(ws + (size_t)36 * 1024 * 1024);       // 64 MB
  float* wv  = (float*)(ws + (size_t)100 * 1024 * 1024);    // 64 KB
  float* u   = (float*)(ws + (size_t)100 * 1024 * 1024 + 65536); // 4.1 KB

  hipLaunchKernelGGL(k_u,    dim3(4),       dim3(256),   0, stream, Wv, Wo, bv, u);
  hipLaunchKernelGGL(k_wt,   dim3(64, 32),  dim3(32, 8), 0, stream, Wq, Wk, Wt);
  hipLaunchKernelGGL(k_xw,   dim3(4096),    dim3(256),   0, stream, x, u, xh, wv);
  hipLaunchKernelGGL(k_proj, dim3(16, 128), dim3(256),   0, stream, xh, Wt, bq, bk, qkh);
  hipLaunchKernelGGL(k_attn, dim3(256),     dim3(256),   0, stream, qkh, wv, bo, out);
}

// Round 3
// 416.289 us; speedup vs baseline: 1.0989x; 1.0989x over previous
//
#include <hip/hip_runtime.h>
#include <stdint.h>

#define D_ 1024
#define S_ 2048
#define B_ 8

typedef _Float16 h16;
typedef _Float16 f16x8 __attribute__((ext_vector_type(8)));
typedef _Float16 f16x4 __attribute__((ext_vector_type(4)));
typedef float    f32x4 __attribute__((ext_vector_type(4)));

typedef __attribute__((address_space(3))) void lds_void;
typedef const __attribute__((address_space(1))) void g_void;

#define MFMA16(a, b, c) __builtin_amdgcn_mfma_f32_16x16x32_f16(a, b, c, 0, 0, 0)

// Stage one 16-row x 32-half (1KB) chunk via global_load_lds (linear LDS dest).
// Swizzle (both-sides, rule #21): stored slot s' holds logical 16B col-chunk
// c = s' ^ ((row>>1)&3).  Write side: lane l -> row=l>>2, s'=l&3, so global col
// chunk = (l&3) ^ ((l>>3)&3).  Read side: logical chunk g read at slot
// g ^ ((row>>1)&3).  Spreads 16-lane row-columns over 8 bank-starts -> no
// ds_read_b128 conflicts.
__device__ __forceinline__ void stage16(const h16* g0, int ld, h16* lchunk) {
  int lane = threadIdx.x & 63;
  int c = (lane & 3) ^ ((lane >> 3) & 3);
  const h16* ga = g0 + (size_t)(lane >> 2) * ld + c * 8;
  __builtin_amdgcn_global_load_lds((g_void*)ga, (lds_void*)lchunk, 16, 0, 0);
}

// ---------------- kernel 1: u[e] = Wv[e,:]·Wo ; u[D] = bv·Wo ----------------
__global__ void k_u(const float* __restrict__ Wv, const float* __restrict__ Wo,
                    const float* __restrict__ bv, float* __restrict__ u) {
  int e = blockIdx.x * 256 + threadIdx.x;
  if (e < D_) {
    const float4* row = (const float4*)(Wv + (size_t)e * D_);
    const float4* wo4 = (const float4*)Wo;
    float s = 0.f;
    #pragma unroll 4
    for (int j = 0; j < D_ / 4; ++j) {
      float4 a = row[j], b = wo4[j];
      s += a.x * b.x + a.y * b.y + a.z * b.z + a.w * b.w;
    }
    u[e] = s;
  }
  if (blockIdx.x == 0 && threadIdx.x == 0) {
    float s = 0.f;
    for (int d = 0; d < D_; ++d) s += bv[d] * Wo[d];
    u[D_] = s;
  }
}

// ------------- kernel 2: Wt[n][k] = (n<D ? Wq : Wk)[k][n]  (fp16) -----------
__global__ void k_wt(const float* __restrict__ Wq, const float* __restrict__ Wk,
                     h16* __restrict__ Wt) {
  __shared__ float t[32][33];
  int n0 = blockIdx.x * 32;
  int k0 = blockIdx.y * 32;
  const float* src = (n0 < D_) ? Wq : Wk;
  int nn = n0 & (D_ - 1);
  int tx = threadIdx.x, ty = threadIdx.y;
  for (int i = ty; i < 32; i += 8)
    t[i][tx] = src[(size_t)(k0 + i) * D_ + nn + tx];
  __syncthreads();
  for (int i = ty; i < 32; i += 8)
    Wt[(size_t)(n0 + i) * D_ + k0 + tx] = (h16)t[tx][i];
}

// -------- kernel 3: xh = fp16(x);  w[r] = x[r,:]·u + u[D]  (one wave/row) ---
__global__ void k_xw(const float* __restrict__ x, const float* __restrict__ u,
                     h16* __restrict__ xh, float* __restrict__ w) {
  int row = blockIdx.x * 4 + (threadIdx.x >> 6);
  int lane = threadIdx.x & 63;
  const float4* xr = (const float4*)(x + (size_t)row * D_);
  const float4* u4 = (const float4*)u;
  h16* xo = xh + (size_t)row * D_;
  float s = 0.f;
  #pragma unroll
  for (int j = 0; j < 4; ++j) {
    int c = j * 64 + lane;
    float4 a = xr[c];
    float4 b = u4[c];
    s += a.x * b.x + a.y * b.y + a.z * b.z + a.w * b.w;
    f16x4 o;
    o[0] = (h16)a.x; o[1] = (h16)a.y; o[2] = (h16)a.z; o[3] = (h16)a.w;
    *(f16x4*)(xo + c * 4) = o;
  }
  #pragma unroll
  for (int off = 32; off; off >>= 1) s += __shfl_xor(s, off, 64);
  if (lane == 0) w[row] = s + u[D_];
}

// ------ kernel 4: qkh[16384][2048] = xh·[Wq|Wk] + [bq|bk]   (fp16 out) ------
// m97 structure: 128x128 tile, BK=32, global_load_lds + swizzle, 2-phase dbuf.
__global__ __launch_bounds__(256, 2) void k_proj(
    const h16* __restrict__ xh, const h16* __restrict__ Wt,
    const float* __restrict__ bq_, const float* __restrict__ bk_,
    h16* __restrict__ qkh) {
  __shared__ alignas(16) h16 As[2][128 * 32];
  __shared__ alignas(16) h16 Bs[2][128 * 32];
  int tid = threadIdx.x;
  int w = tid >> 6;
  int lane = tid & 63;
  int wr = w >> 1, wc = w & 1;
  int g = lane >> 4, l15 = lane & 15;
  int swz = (l15 >> 1) & 3;

  // XCD swizzle: 2048 blocks, 8 XCDs, each XCD owns a contiguous M-stripe.
  int idx = (blockIdx.x & 7) * 256 + (blockIdx.x >> 3);
  int m0 = (idx >> 4) * 128, n0 = (idx & 15) * 128;

  f32x4 acc[4][4] = {};

  // stage K-step k into buffer buf (A: 8 chunks, B: 8 chunks; 4 waves x 2+2)
  #define STAGE_PROJ(buf, k)                                                    \
    {                                                                           \
      int k0_ = (k) * 32;                                                       \
      _Pragma("unroll")                                                         \
      for (int j = 0; j < 2; ++j) {                                             \
        int ch = w * 2 + j;                                                     \
        stage16(xh + (size_t)(m0 + ch * 16) * D_ + k0_, D_, &As[buf][ch * 512]);\
        stage16(Wt + (size_t)(n0 + ch * 16) * D_ + k0_, D_, &Bs[buf][ch * 512]);\
      }                                                                         \
    }

  STAGE_PROJ(0, 0);
  __syncthreads();
  for (int k = 0; k < 32; ++k) {
    int buf = k & 1;
    if (k + 1 < 32) STAGE_PROJ(buf ^ 1, k + 1);
    f16x8 af[4], bf[4];
    #pragma unroll
    for (int i = 0; i < 4; ++i) {
      af[i] = *(const f16x8*)(&As[buf][(wr * 64 + i * 16 + l15) * 32 + (g ^ swz) * 8]);
      bf[i] = *(const f16x8*)(&Bs[buf][(wc * 64 + i * 16 + l15) * 32 + (g ^ swz) * 8]);
    }
    #pragma unroll
    for (int mi = 0; mi < 4; ++mi)
      #pragma unroll
      for (int ni = 0; ni < 4; ++ni)
        acc[mi][ni] = MFMA16(af[mi], bf[ni], acc[mi][ni]);
    __syncthreads();
  }

  #pragma unroll
  for (int ni = 0; ni < 4; ++ni) {
    int n = n0 + wc * 64 + ni * 16 + l15;
    float bias = (n < D_) ? bq_[n] : bk_[n - D_];
    #pragma unroll
    for (int mi = 0; mi < 4; ++mi) {
      #pragma unroll
      for (int r = 0; r < 4; ++r) {
        int m = m0 + wr * 64 + mi * 16 + g * 4 + r;
        qkh[(size_t)m * (2 * D_) + n] = (h16)(acc[mi][ni][r] + bias);
      }
    }
  }
}

// -- kernel 5: out[b,s] = (Σ_t e^{S_st} w[b,t]) / (Σ_t e^{S_st}) + bo --------
// 512 thr / 8 waves, KT=512 (keys split 8-way), gload_lds + swizzle, dbuf.
__global__ __launch_bounds__(512, 2) void k_attn(
    const h16* __restrict__ qkh, const float* __restrict__ wv,
    const float* __restrict__ bo, float* __restrict__ out) {
  __shared__ alignas(16) h16 Qs[2][64 * 32];    // 8 KB
  __shared__ alignas(16) h16 Ks[2][512 * 32];   // 64 KB
  __shared__ float sm[3][8][64];                // 6 KB
  int tid = threadIdx.x;
  int w = tid >> 6;
  int lane = tid & 63;
  int g = lane >> 4, l15 = lane & 15;
  int swz = (l15 >> 1) & 3;
  int b = blockIdx.x & 7;                        // batch -> XCD affinity
  int q0 = (blockIdx.x >> 3) * 64;
  size_t rbase = (size_t)b * S_;

  // stage K-step st (tile tt = st>>5, depth chunk k0 = (st&31)*32)
  #define STAGE_ATTN(buf, st)                                                   \
    {                                                                           \
      int tt_ = (st) >> 5, k0_ = ((st) & 31) * 32;                              \
      _Pragma("unroll")                                                         \
      for (int j = 0; j < 4; ++j) {                                             \
        int ck = w * 4 + j;                                                     \
        stage16(qkh + (rbase + tt_ * 512 + ck * 16) * (2 * D_) + D_ + k0_,      \
                2 * D_, &Ks[buf][ck * 512]);                                    \
      }                                                                         \
      if (w < 4)                                                                \
        stage16(qkh + (rbase + q0 + w * 16) * (2 * D_) + k0_,                   \
                2 * D_, &Qs[buf][w * 512]);                                     \
    }

  float mrun[4][4], num[4][4], den[4][4];
  #pragma unroll
  for (int mi = 0; mi < 4; ++mi)
    #pragma unroll
    for (int r = 0; r < 4; ++r) { mrun[mi][r] = -1e30f; num[mi][r] = 0.f; den[mi][r] = 0.f; }

  STAGE_ATTN(0, 0);
  __syncthreads();

  for (int tt = 0; tt < 4; ++tt) {
    f32x4 acc[4][4] = {};
    for (int kc = 0; kc < 32; ++kc) {
      int st = tt * 32 + kc, buf = st & 1;
      if (st + 1 < 128) STAGE_ATTN(buf ^ 1, st + 1);
      f16x8 qf[4], kf[4];
      #pragma unroll
      for (int i = 0; i < 4; ++i) {
        qf[i] = *(const f16x8*)(&Qs[buf][(i * 16 + l15) * 32 + (g ^ swz) * 8]);
        kf[i] = *(const f16x8*)(&Ks[buf][(w * 64 + i * 16 + l15) * 32 + (g ^ swz) * 8]);
      }
      #pragma unroll
      for (int mi = 0; mi < 4; ++mi)
        #pragma unroll
        for (int ni = 0; ni < 4; ++ni)
          acc[mi][ni] = MFMA16(qf[mi], kf[ni], acc[mi][ni]);
      __syncthreads();
    }
    // online softmax + fused Σp·w   (key t = tt*512 + w*64 + ni*16 + l15)
    float wvv[4];
    #pragma unroll
    for (int ni = 0; ni < 4; ++ni)
      wvv[ni] = wv[rbase + tt * 512 + w * 64 + ni * 16 + l15];
    #pragma unroll
    for (int mi = 0; mi < 4; ++mi) {
      #pragma unroll
      for (int r = 0; r < 4; ++r) {
        float v = fmaxf(fmaxf(acc[mi][0][r], acc[mi][1][r]),
                        fmaxf(acc[mi][2][r], acc[mi][3][r]));
        #pragma unroll
        for (int off = 1; off < 16; off <<= 1) v = fmaxf(v, __shfl_xor(v, off, 64));
        float mn = fmaxf(mrun[mi][r], v);
        float scl = __expf(mrun[mi][r] - mn);
        float pn = 0.f, pd = 0.f;
        #pragma unroll
        for (int ni = 0; ni < 4; ++ni) {
          float p = __expf(acc[mi][ni][r] - mn);
          pn += p * wvv[ni];
          pd += p;
        }
        num[mi][r] = num[mi][r] * scl + pn;
        den[mi][r] = den[mi][r] * scl + pd;
        mrun[mi][r] = mn;
      }
    }
  }
  // reduce partials across the 16 key-lanes of each fragment
  #pragma unroll
  for (int mi = 0; mi < 4; ++mi)
    #pragma unroll
    for (int r = 0; r < 4; ++r) {
      #pragma unroll
      for (int off = 1; off < 16; off <<= 1) {
        num[mi][r] += __shfl_xor(num[mi][r], off, 64);
        den[mi][r] += __shfl_xor(den[mi][r], off, 64);
      }
    }
  if (l15 == 0) {
    #pragma unroll
    for (int mi = 0; mi < 4; ++mi)
      #pragma unroll
      for (int r = 0; r < 4; ++r) {
        int row = mi * 16 + g * 4 + r;
        sm[0][w][row] = mrun[mi][r];
        sm[1][w][row] = num[mi][r];
        sm[2][w][row] = den[mi][r];
      }
  }
  __syncthreads();
  if (tid < 64) {
    float M = sm[0][0][tid];
    #pragma unroll
    for (int j = 1; j < 8; ++j) M = fmaxf(M, sm[0][j][tid]);
    float N = 0.f, Dn = 0.f;
    #pragma unroll
    for (int j = 0; j < 8; ++j) {
      float e = __expf(sm[0][j][tid] - M);
      N += sm[1][j][tid] * e;
      Dn += sm[2][j][tid] * e;
    }
    out[rbase + q0 + tid] = N / Dn + bo[0];
  }
}

extern "C" void kernel_launch(void* const* d_in, const int* in_sizes, int n_in,
                              void* d_out, int out_size, void* d_ws, size_t ws_size,
                              hipStream_t stream) {
  const float* x  = (const float*)d_in[0];
  const float* Wq = (const float*)d_in[1];
  const float* bq = (const float*)d_in[2];
  const float* Wk = (const float*)d_in[3];
  const float* bk = (const float*)d_in[4];
  const float* Wv = (const float*)d_in[5];
  const float* bv = (const float*)d_in[6];
  const float* Wo = (const float*)d_in[7];
  const float* bo = (const float*)d_in[8];
  float* out = (float*)d_out;

  char* ws = (char*)d_ws;
  h16*   xh  = (h16*)ws;                                         // 32 MB
  h16*   Wt  = (h16*)(ws + (size_t)32 * 1024 * 1024);            // 4 MB
  h16*   qkh = (h16*)(ws + (size_t)36 * 1024 * 1024);            // 64 MB
  float* wv  = (float*)(ws + (size_t)100 * 1024 * 1024);         // 64 KB
  float* u   = (float*)(ws + (size_t)100 * 1024 * 1024 + 65536); // 4.1 KB

  hipLaunchKernelGGL(k_u,    dim3(4),      dim3(256),   0, stream, Wv, Wo, bv, u);
  hipLaunchKernelGGL(k_wt,   dim3(64, 32), dim3(32, 8), 0, stream, Wq, Wk, Wt);
  hipLaunchKernelGGL(k_xw,   dim3(4096),   dim3(256),   0, stream, x, u, xh, wv);
  hipLaunchKernelGGL(k_proj, dim3(2048),   dim3(256),   0, stream, xh, Wt, bq, bk, qkh);
  hipLaunchKernelGGL(k_attn, dim3(256),    dim3(512),   0, stream, qkh, wv, bo, out);
}

// Round 4
// 385.429 us; speedup vs baseline: 1.1869x; 1.0801x over previous
//
#include <hip/hip_runtime.h>
#include <stdint.h>

#define D_ 1024
#define S_ 2048
#define B_ 8

typedef _Float16 h16;
typedef _Float16 f16x8 __attribute__((ext_vector_type(8)));
typedef _Float16 f16x4 __attribute__((ext_vector_type(4)));
typedef float    f32x4 __attribute__((ext_vector_type(4)));

typedef __attribute__((address_space(3))) void lds_void;
typedef const __attribute__((address_space(1))) void g_void;

#define MFMA16(a, b, c) __builtin_amdgcn_mfma_f32_16x16x32_f16(a, b, c, 0, 0, 0)

// Stage one 16-row x 32-half (1KB) chunk via global_load_lds (linear LDS dest).
// Swizzle (both-sides, rule #21): stored slot s' holds logical 16B col-chunk
// c = s' ^ ((row>>1)&3).  Write: lane l -> row=l>>2, slot=l&3, global chunk
// c=(l&3)^((l>>3)&3).  Read: logical chunk g at slot g ^ ((row>>1)&3).
__device__ __forceinline__ void stage16(const h16* g0, int ld, h16* lchunk) {
  int lane = threadIdx.x & 63;
  int c = (lane & 3) ^ ((lane >> 3) & 3);
  const h16* ga = g0 + (size_t)(lane >> 2) * ld + c * 8;
  __builtin_amdgcn_global_load_lds((g_void*)ga, (lds_void*)lchunk, 16, 0, 0);
}

// ---------------- kernel 1: u[e] = Wv[e,:]·Wo ; u[D] = bv·Wo ----------------
__global__ void k_u(const float* __restrict__ Wv, const float* __restrict__ Wo,
                    const float* __restrict__ bv, float* __restrict__ u) {
  int e = blockIdx.x * 256 + threadIdx.x;
  if (e < D_) {
    const float4* row = (const float4*)(Wv + (size_t)e * D_);
    const float4* wo4 = (const float4*)Wo;
    float s = 0.f;
    #pragma unroll 4
    for (int j = 0; j < D_ / 4; ++j) {
      float4 a = row[j], b = wo4[j];
      s += a.x * b.x + a.y * b.y + a.z * b.z + a.w * b.w;
    }
    u[e] = s;
  }
  if (blockIdx.x == 0 && threadIdx.x == 0) {
    float s = 0.f;
    for (int d = 0; d < D_; ++d) s += bv[d] * Wo[d];
    u[D_] = s;
  }
}

// ------------- kernel 2: Wt[n][k] = (n<D ? Wq : Wk)[k][n]  (fp16) -----------
__global__ void k_wt(const float* __restrict__ Wq, const float* __restrict__ Wk,
                     h16* __restrict__ Wt) {
  __shared__ float t[32][33];
  int n0 = blockIdx.x * 32;
  int k0 = blockIdx.y * 32;
  const float* src = (n0 < D_) ? Wq : Wk;
  int nn = n0 & (D_ - 1);
  int tx = threadIdx.x, ty = threadIdx.y;
  for (int i = ty; i < 32; i += 8)
    t[i][tx] = src[(size_t)(k0 + i) * D_ + nn + tx];
  __syncthreads();
  for (int i = ty; i < 32; i += 8)
    Wt[(size_t)(n0 + i) * D_ + k0 + tx] = (h16)t[tx][i];
}

// -------- kernel 3: xh = fp16(x);  w[r] = x[r,:]·u + u[D]  (one wave/row) ---
__global__ void k_xw(const float* __restrict__ x, const float* __restrict__ u,
                     h16* __restrict__ xh, float* __restrict__ w) {
  int row = blockIdx.x * 4 + (threadIdx.x >> 6);
  int lane = threadIdx.x & 63;
  const float4* xr = (const float4*)(x + (size_t)row * D_);
  const float4* u4 = (const float4*)u;
  h16* xo = xh + (size_t)row * D_;
  float s = 0.f;
  #pragma unroll
  for (int j = 0; j < 4; ++j) {
    int c = j * 64 + lane;
    float4 a = xr[c];
    float4 b = u4[c];
    s += a.x * b.x + a.y * b.y + a.z * b.z + a.w * b.w;
    f16x4 o;
    o[0] = (h16)a.x; o[1] = (h16)a.y; o[2] = (h16)a.z; o[3] = (h16)a.w;
    *(f16x4*)(xo + c * 4) = o;
  }
  #pragma unroll
  for (int off = 32; off; off >>= 1) s += __shfl_xor(s, off, 64);
  if (lane == 0) w[row] = s + u[D_];
}

// ------ kernel 4: qkh[16384][2048] = xh·[Wq|Wk] + [bq|bk]   (fp16 out) ------
// m97 structure: 128x128 tile, BK=32, global_load_lds + swizzle, 2-phase dbuf.
// launch_bounds(256,4): cap VGPR at 128 -> 4 blocks/CU (LDS 32KB allows 5).
__global__ __launch_bounds__(256, 4) void k_proj(
    const h16* __restrict__ xh, const h16* __restrict__ Wt,
    const float* __restrict__ bq_, const float* __restrict__ bk_,
    h16* __restrict__ qkh) {
  __shared__ alignas(16) h16 As[2][128 * 32];
  __shared__ alignas(16) h16 Bs[2][128 * 32];
  int tid = threadIdx.x;
  int w = tid >> 6;
  int lane = tid & 63;
  int wr = w >> 1, wc = w & 1;
  int g = lane >> 4, l15 = lane & 15;
  int swz = (l15 >> 1) & 3;

  // XCD swizzle: XCD x owns m-stripe [x*16,(x+1)*16); n-tiles vary fastest
  // so a resident A-tile is L2-reused across 16 consecutive blocks.
  int idx = (blockIdx.x & 7) * 256 + (blockIdx.x >> 3);
  int m0 = (idx >> 4) * 128, n0 = (idx & 15) * 128;

  f32x4 acc[4][4] = {};

  #define STAGE_PROJ(buf, k)                                                    \
    {                                                                           \
      int k0_ = (k) * 32;                                                       \
      _Pragma("unroll")                                                         \
      for (int j = 0; j < 2; ++j) {                                             \
        int ch = w * 2 + j;                                                     \
        stage16(xh + (size_t)(m0 + ch * 16) * D_ + k0_, D_, &As[buf][ch * 512]);\
        stage16(Wt + (size_t)(n0 + ch * 16) * D_ + k0_, D_, &Bs[buf][ch * 512]);\
      }                                                                         \
    }

  STAGE_PROJ(0, 0);
  __syncthreads();
  for (int k = 0; k < 32; ++k) {
    int buf = k & 1;
    if (k + 1 < 32) STAGE_PROJ(buf ^ 1, k + 1);
    f16x8 af[4], bf[4];
    #pragma unroll
    for (int i = 0; i < 4; ++i) {
      af[i] = *(const f16x8*)(&As[buf][(wr * 64 + i * 16 + l15) * 32 + (g ^ swz) * 8]);
      bf[i] = *(const f16x8*)(&Bs[buf][(wc * 64 + i * 16 + l15) * 32 + (g ^ swz) * 8]);
    }
    #pragma unroll
    for (int mi = 0; mi < 4; ++mi)
      #pragma unroll
      for (int ni = 0; ni < 4; ++ni)
        acc[mi][ni] = MFMA16(af[mi], bf[ni], acc[mi][ni]);
    __syncthreads();
  }

  #pragma unroll
  for (int ni = 0; ni < 4; ++ni) {
    int n = n0 + wc * 64 + ni * 16 + l15;
    float bias = (n < D_) ? bq_[n] : bk_[n - D_];
    #pragma unroll
    for (int mi = 0; mi < 4; ++mi) {
      #pragma unroll
      for (int r = 0; r < 4; ++r) {
        int m = m0 + wr * 64 + mi * 16 + g * 4 + r;
        qkh[(size_t)m * (2 * D_) + n] = (h16)(acc[mi][ni][r] + bias);
      }
    }
  }
}

// -- kernel 5: partial softmax-weighted sum over a 1024-key half -------------
// 512 blocks (2/CU): b = blk&7 (XCD affinity), h = (blk>>3)&1, q-tile = blk>>4.
// Writes (m, num, den) partials; k_fin merges the two halves.
__global__ __launch_bounds__(512, 4) void k_attn(
    const h16* __restrict__ qkh, const float* __restrict__ wv,
    float* __restrict__ part) {
  __shared__ alignas(16) h16 Qs[2][64 * 32];    // 8 KB
  __shared__ alignas(16) h16 Ks[2][512 * 32];   // 64 KB
  __shared__ float sm[3][8][64];                // 6 KB
  int tid = threadIdx.x;
  int w = tid >> 6;
  int lane = tid & 63;
  int g = lane >> 4, l15 = lane & 15;
  int swz = (l15 >> 1) & 3;
  int b = blockIdx.x & 7;                        // batch -> XCD affinity
  int h = (blockIdx.x >> 3) & 1;                 // key half
  int q0 = (blockIdx.x >> 4) * 64;
  int t0 = h * 1024;
  size_t rbase = (size_t)b * S_;

  // stage step st in [0,64): tile tt = st>>5, depth chunk k0 = (st&31)*32
  #define STAGE_ATTN(buf, st)                                                   \
    {                                                                           \
      int tt_ = (st) >> 5, k0_ = ((st) & 31) * 32;                              \
      _Pragma("unroll")                                                         \
      for (int j = 0; j < 4; ++j) {                                             \
        int ck = w * 4 + j;                                                     \
        stage16(qkh + (rbase + t0 + tt_ * 512 + ck * 16) * (2 * D_) + D_ + k0_, \
                2 * D_, &Ks[buf][ck * 512]);                                    \
      }                                                                         \
      if (w < 4)                                                                \
        stage16(qkh + (rbase + q0 + w * 16) * (2 * D_) + k0_,                   \
                2 * D_, &Qs[buf][w * 512]);                                     \
    }

  float mrun[4][4], num[4][4], den[4][4];
  #pragma unroll
  for (int mi = 0; mi < 4; ++mi)
    #pragma unroll
    for (int r = 0; r < 4; ++r) { mrun[mi][r] = -1e30f; num[mi][r] = 0.f; den[mi][r] = 0.f; }

  STAGE_ATTN(0, 0);
  __syncthreads();

  for (int tt = 0; tt < 2; ++tt) {
    f32x4 acc[4][4] = {};
    for (int kc = 0; kc < 32; ++kc) {
      int st = tt * 32 + kc, buf = st & 1;
      if (st + 1 < 64) STAGE_ATTN(buf ^ 1, st + 1);
      f16x8 qf[4], kf[4];
      #pragma unroll
      for (int i = 0; i < 4; ++i) {
        qf[i] = *(const f16x8*)(&Qs[buf][(i * 16 + l15) * 32 + (g ^ swz) * 8]);
        kf[i] = *(const f16x8*)(&Ks[buf][(w * 64 + i * 16 + l15) * 32 + (g ^ swz) * 8]);
      }
      __builtin_amdgcn_s_setprio(1);
      #pragma unroll
      for (int mi = 0; mi < 4; ++mi)
        #pragma unroll
        for (int ni = 0; ni < 4; ++ni)
          acc[mi][ni] = MFMA16(qf[mi], kf[ni], acc[mi][ni]);
      __builtin_amdgcn_s_setprio(0);
      __syncthreads();
    }
    // online softmax + fused Σp·w  (key t = t0 + tt*512 + w*64 + ni*16 + l15)
    float wvv[4];
    #pragma unroll
    for (int ni = 0; ni < 4; ++ni)
      wvv[ni] = wv[rbase + t0 + tt * 512 + w * 64 + ni * 16 + l15];
    #pragma unroll
    for (int mi = 0; mi < 4; ++mi) {
      #pragma unroll
      for (int r = 0; r < 4; ++r) {
        float v = fmaxf(fmaxf(acc[mi][0][r], acc[mi][1][r]),
                        fmaxf(acc[mi][2][r], acc[mi][3][r]));
        #pragma unroll
        for (int off = 1; off < 16; off <<= 1) v = fmaxf(v, __shfl_xor(v, off, 64));
        float mn = fmaxf(mrun[mi][r], v);
        float scl = __expf(mrun[mi][r] - mn);
        float pn = 0.f, pd = 0.f;
        #pragma unroll
        for (int ni = 0; ni < 4; ++ni) {
          float p = __expf(acc[mi][ni][r] - mn);
          pn += p * wvv[ni];
          pd += p;
        }
        num[mi][r] = num[mi][r] * scl + pn;
        den[mi][r] = den[mi][r] * scl + pd;
        mrun[mi][r] = mn;
      }
    }
  }
  // reduce partials across the 16 key-lanes of each fragment
  #pragma unroll
  for (int mi = 0; mi < 4; ++mi)
    #pragma unroll
    for (int r = 0; r < 4; ++r) {
      #pragma unroll
      for (int off = 1; off < 16; off <<= 1) {
        num[mi][r] += __shfl_xor(num[mi][r], off, 64);
        den[mi][r] += __shfl_xor(den[mi][r], off, 64);
      }
    }
  if (l15 == 0) {
    #pragma unroll
    for (int mi = 0; mi < 4; ++mi)
      #pragma unroll
      for (int r = 0; r < 4; ++r) {
        int row = mi * 16 + g * 4 + r;
        sm[0][w][row] = mrun[mi][r];
        sm[1][w][row] = num[mi][r];
        sm[2][w][row] = den[mi][r];
      }
  }
  __syncthreads();
  if (tid < 64) {
    float M = sm[0][0][tid];
    #pragma unroll
    for (int j = 1; j < 8; ++j) M = fmaxf(M, sm[0][j][tid]);
    float N = 0.f, Dn = 0.f;
    #pragma unroll
    for (int j = 0; j < 8; ++j) {
      float e = __expf(sm[0][j][tid] - M);
      N += sm[1][j][tid] * e;
      Dn += sm[2][j][tid] * e;
    }
    size_t row = rbase + q0 + tid;
    part[row * 6 + h * 3 + 0] = M;
    part[row * 6 + h * 3 + 1] = N;
    part[row * 6 + h * 3 + 2] = Dn;
  }
}

// ------------- kernel 6: merge the two key-half partials --------------------
__global__ void k_fin(const float* __restrict__ part, const float* __restrict__ bo,
                      float* __restrict__ out) {
  int idx = blockIdx.x * 256 + threadIdx.x;
  if (idx >= B_ * S_) return;
  float m1 = part[idx * 6 + 0], n1 = part[idx * 6 + 1], d1 = part[idx * 6 + 2];
  float m2 = part[idx * 6 + 3], n2 = part[idx * 6 + 4], d2 = part[idx * 6 + 5];
  float M = fmaxf(m1, m2);
  float e1 = __expf(m1 - M), e2 = __expf(m2 - M);
  out[idx] = (n1 * e1 + n2 * e2) / (d1 * e1 + d2 * e2) + bo[0];
}

extern "C" void kernel_launch(void* const* d_in, const int* in_sizes, int n_in,
                              void* d_out, int out_size, void* d_ws, size_t ws_size,
                              hipStream_t stream) {
  const float* x  = (const float*)d_in[0];
  const float* Wq = (const float*)d_in[1];
  const float* bq = (const float*)d_in[2];
  const float* Wk = (const float*)d_in[3];
  const float* bk = (const float*)d_in[4];
  const float* Wv = (const float*)d_in[5];
  const float* bv = (const float*)d_in[6];
  const float* Wo = (const float*)d_in[7];
  const float* bo = (const float*)d_in[8];
  float* out = (float*)d_out;

  char* ws = (char*)d_ws;
  h16*   xh   = (h16*)ws;                                         // 32 MB
  h16*   Wt   = (h16*)(ws + (size_t)32 * 1024 * 1024);            // 4 MB
  h16*   qkh  = (h16*)(ws + (size_t)36 * 1024 * 1024);            // 64 MB
  float* wv   = (float*)(ws + (size_t)100 * 1024 * 1024);         // 64 KB
  float* u    = (float*)(ws + (size_t)100 * 1024 * 1024 + 65536); // 4.1 KB
  float* part = (float*)(ws + (size_t)101 * 1024 * 1024);         // 384 KB

  hipLaunchKernelGGL(k_u,    dim3(4),      dim3(256),   0, stream, Wv, Wo, bv, u);
  hipLaunchKernelGGL(k_wt,   dim3(64, 32), dim3(32, 8), 0, stream, Wq, Wk, Wt);
  hipLaunchKernelGGL(k_xw,   dim3(4096),   dim3(256),   0, stream, x, u, xh, wv);
  hipLaunchKernelGGL(k_proj, dim3(2048),   dim3(256),   0, stream, xh, Wt, bq, bk, qkh);
  hipLaunchKernelGGL(k_attn, dim3(512),    dim3(512),   0, stream, qkh, wv, part);
  hipLaunchKernelGGL(k_fin,  dim3(64),     dim3(256),   0, stream, part, bo, out);
}

// Round 5
// 328.968 us; speedup vs baseline: 1.3906x; 1.1716x over previous
//
#include <hip/hip_runtime.h>
#include <stdint.h>

#define D_ 1024
#define S_ 2048
#define B_ 8

typedef _Float16 h16;
typedef _Float16 f16x8 __attribute__((ext_vector_type(8)));
typedef _Float16 f16x4 __attribute__((ext_vector_type(4)));
typedef float    f32x4 __attribute__((ext_vector_type(4)));

typedef __attribute__((address_space(3))) void lds_void;
typedef const __attribute__((address_space(1))) void g_void;

#define MFMA16(a, b, c) __builtin_amdgcn_mfma_f32_16x16x32_f16(a, b, c, 0, 0, 0)
#define VMCNT(n) asm volatile("s_waitcnt vmcnt(" #n ")" ::: "memory")
#define SFENCE() __builtin_amdgcn_sched_barrier(0)
#define SBAR() __builtin_amdgcn_s_barrier()

// Stage one 16-row x 32-half (1KB) chunk via global_load_lds (linear LDS dest).
// Swizzle (both-sides, rule #21): stored slot s' holds logical 16B col-chunk
// c = s' ^ ((row>>1)&3).  Write: lane l -> row=l>>2, slot=l&3, global chunk
// c=(l&3)^((l>>3)&3).  Read: logical chunk g at slot g ^ ((row>>1)&3).
__device__ __forceinline__ void stage16(const h16* g0, int ld, h16* lchunk) {
  int lane = threadIdx.x & 63;
  int c = (lane & 3) ^ ((lane >> 3) & 3);
  const h16* ga = g0 + (size_t)(lane >> 2) * ld + c * 8;
  __builtin_amdgcn_global_load_lds((g_void*)ga, (lds_void*)lchunk, 16, 0, 0);
}

// ------- kernel 1: u[e] = Wv[e,:]·Wo (wave per row); u[D] = bv·Wo -----------
__global__ void k_u(const float* __restrict__ Wv, const float* __restrict__ Wo,
                    const float* __restrict__ bv, float* __restrict__ u) {
  int lane = threadIdx.x & 63;
  if (blockIdx.x == 256) {            // bias block: u[D] = bv·Wo, one wave
    if (threadIdx.x < 64) {
      float s = 0.f;
      #pragma unroll
      for (int j = 0; j < 4; ++j) {
        float4 a = ((const float4*)bv)[j * 64 + lane];
        float4 b = ((const float4*)Wo)[j * 64 + lane];
        s += a.x * b.x + a.y * b.y + a.z * b.z + a.w * b.w;
      }
      #pragma unroll
      for (int off = 32; off; off >>= 1) s += __shfl_xor(s, off, 64);
      if (lane == 0) u[D_] = s;
    }
    return;
  }
  int row = blockIdx.x * 4 + (threadIdx.x >> 6);
  const float4* r4 = (const float4*)(Wv + (size_t)row * D_);
  const float4* w4 = (const float4*)Wo;
  float s = 0.f;
  #pragma unroll
  for (int j = 0; j < 4; ++j) {
    int c = j * 64 + lane;
    float4 a = r4[c], b = w4[c];
    s += a.x * b.x + a.y * b.y + a.z * b.z + a.w * b.w;
  }
  #pragma unroll
  for (int off = 32; off; off >>= 1) s += __shfl_xor(s, off, 64);
  if (lane == 0) u[row] = s;
}

// ------------- kernel 2: Wt[n][k] = (n<D ? Wq : Wk)[k][n]  (fp16) -----------
__global__ void k_wt(const float* __restrict__ Wq, const float* __restrict__ Wk,
                     h16* __restrict__ Wt) {
  __shared__ float t[32][33];
  int n0 = blockIdx.x * 32;
  int k0 = blockIdx.y * 32;
  const float* src = (n0 < D_) ? Wq : Wk;
  int nn = n0 & (D_ - 1);
  int tx = threadIdx.x, ty = threadIdx.y;
  for (int i = ty; i < 32; i += 8)
    t[i][tx] = src[(size_t)(k0 + i) * D_ + nn + tx];
  __syncthreads();
  for (int i = ty; i < 32; i += 8)
    Wt[(size_t)(n0 + i) * D_ + k0 + tx] = (h16)t[tx][i];
}

// -------- kernel 3: xh = fp16(x);  w[r] = x[r,:]·u + u[D]  (one wave/row) ---
__global__ void k_xw(const float* __restrict__ x, const float* __restrict__ u,
                     h16* __restrict__ xh, float* __restrict__ w) {
  int row = blockIdx.x * 4 + (threadIdx.x >> 6);
  int lane = threadIdx.x & 63;
  const float4* xr = (const float4*)(x + (size_t)row * D_);
  const float4* u4 = (const float4*)u;
  h16* xo = xh + (size_t)row * D_;
  float s = 0.f;
  #pragma unroll
  for (int j = 0; j < 4; ++j) {
    int c = j * 64 + lane;
    float4 a = xr[c];
    float4 b = u4[c];
    s += a.x * b.x + a.y * b.y + a.z * b.z + a.w * b.w;
    f16x4 o;
    o[0] = (h16)a.x; o[1] = (h16)a.y; o[2] = (h16)a.z; o[3] = (h16)a.w;
    *(f16x4*)(xo + c * 4) = o;
  }
  #pragma unroll
  for (int off = 32; off; off >>= 1) s += __shfl_xor(s, off, 64);
  if (lane == 0) w[row] = s + u[D_];
}

// ------ kernel 4: qkh[16384][2048] = xh·[Wq|Wk] + [bq|bk]   (fp16 out) ------
// 128x128 tile, BK=32, gload_lds + swizzle, 2-buffer COUNTED-vmcnt schedule
// (T3/T4): loads stay in flight across raw barriers; never vmcnt(0) in-loop.
__global__ __launch_bounds__(256, 4) void k_proj(
    const h16* __restrict__ xh, const h16* __restrict__ Wt,
    const float* __restrict__ bq_, const float* __restrict__ bk_,
    h16* __restrict__ qkh) {
  __shared__ alignas(16) h16 As[2][128 * 32];
  __shared__ alignas(16) h16 Bs[2][128 * 32];
  int tid = threadIdx.x;
  int w = tid >> 6;
  int lane = tid & 63;
  int wr = w >> 1, wc = w & 1;
  int g = lane >> 4, l15 = lane & 15;
  int swz = (l15 >> 1) & 3;

  // XCD swizzle: XCD x owns an m-stripe; n-tiles vary fastest for A-reuse.
  int idx = (blockIdx.x & 7) * 256 + (blockIdx.x >> 3);
  int m0 = (idx >> 4) * 128, n0 = (idx & 15) * 128;

  f32x4 acc[4][4] = {};

  // per wave: 2 A-chunks + 2 B-chunks = 4 loads/step (uniform)
  #define STAGE_PROJ(buf, k)                                                    \
    {                                                                           \
      int k0_ = (k) * 32;                                                       \
      _Pragma("unroll")                                                         \
      for (int j = 0; j < 2; ++j) {                                             \
        int ch = w * 2 + j;                                                     \
        stage16(xh + (size_t)(m0 + ch * 16) * D_ + k0_, D_, &As[buf][ch * 512]);\
        stage16(Wt + (size_t)(n0 + ch * 16) * D_ + k0_, D_, &Bs[buf][ch * 512]);\
      }                                                                         \
    }

  STAGE_PROJ(0, 0);
  for (int k = 0; k < 32; ++k) {
    int buf = k & 1;
    if (k + 1 < 32) {
      STAGE_PROJ(buf ^ 1, k + 1);
      VMCNT(4);              // wait: only the 4 just-issued may remain
    } else {
      VMCNT(0);
    }
    SFENCE();
    SBAR();                  // raw barrier: no compiler vmcnt(0) drain
    SFENCE();
    f16x8 af[4], bf[4];
    #pragma unroll
    for (int i = 0; i < 4; ++i) {
      af[i] = *(const f16x8*)(&As[buf][(wr * 64 + i * 16 + l15) * 32 + (g ^ swz) * 8]);
      bf[i] = *(const f16x8*)(&Bs[buf][(wc * 64 + i * 16 + l15) * 32 + (g ^ swz) * 8]);
    }
    __builtin_amdgcn_s_setprio(1);
    #pragma unroll
    for (int mi = 0; mi < 4; ++mi)
      #pragma unroll
      for (int ni = 0; ni < 4; ++ni)
        acc[mi][ni] = MFMA16(af[mi], bf[ni], acc[mi][ni]);
    __builtin_amdgcn_s_setprio(0);
    SBAR();                  // all reads of buf done before it's re-staged
  }

  #pragma unroll
  for (int ni = 0; ni < 4; ++ni) {
    int n = n0 + wc * 64 + ni * 16 + l15;
    float bias = (n < D_) ? bq_[n] : bk_[n - D_];
    #pragma unroll
    for (int mi = 0; mi < 4; ++mi) {
      #pragma unroll
      for (int r = 0; r < 4; ++r) {
        int m = m0 + wr * 64 + mi * 16 + g * 4 + r;
        qkh[(size_t)m * (2 * D_) + n] = (h16)(acc[mi][ni][r] + bias);
      }
    }
  }
}

// -- kernel 5: partial softmax-weighted sum over a 1024-key half -------------
// 512 blocks (2/CU). Counted-vmcnt schedule; waves 0-3 stage Q (5 loads/step),
// waves 4-7 K only (4 loads/step) -> wave-uniform vmcnt targets.
__global__ __launch_bounds__(512, 4) void k_attn(
    const h16* __restrict__ qkh, const float* __restrict__ wv,
    float* __restrict__ part) {
  __shared__ alignas(16) h16 Qs[2][64 * 32];    // 8 KB
  __shared__ alignas(16) h16 Ks[2][512 * 32];   // 64 KB
  __shared__ float sm[3][8][64];                // 6 KB
  int tid = threadIdx.x;
  int w = tid >> 6;
  int lane = tid & 63;
  int g = lane >> 4, l15 = lane & 15;
  int swz = (l15 >> 1) & 3;
  int b = blockIdx.x & 7;                        // batch -> XCD affinity
  int h = (blockIdx.x >> 3) & 1;                 // key half
  int q0 = (blockIdx.x >> 4) * 64;
  int t0 = h * 1024;
  size_t rbase = (size_t)b * S_;

  // step st in [0,64): tile tt = st>>5, depth chunk k0 = (st&31)*32
  #define STAGE_ATTN(buf, st)                                                   \
    {                                                                           \
      int tt_ = (st) >> 5, k0_ = ((st) & 31) * 32;                              \
      _Pragma("unroll")                                                         \
      for (int j = 0; j < 4; ++j) {                                             \
        int ck = w * 4 + j;                                                     \
        stage16(qkh + (rbase + t0 + tt_ * 512 + ck * 16) * (2 * D_) + D_ + k0_, \
                2 * D_, &Ks[buf][ck * 512]);                                    \
      }                                                                         \
      if (w < 4)                                                                \
        stage16(qkh + (rbase + q0 + w * 16) * (2 * D_) + k0_,                   \
                2 * D_, &Qs[buf][w * 512]);                                     \
    }

  float mrun[4][4], num[4][4], den[4][4];
  #pragma unroll
  for (int mi = 0; mi < 4; ++mi)
    #pragma unroll
    for (int r = 0; r < 4; ++r) { mrun[mi][r] = -1e30f; num[mi][r] = 0.f; den[mi][r] = 0.f; }

  STAGE_ATTN(0, 0);

  for (int tt = 0; tt < 2; ++tt) {
    f32x4 acc[4][4] = {};
    for (int kc = 0; kc < 32; ++kc) {
      int st = tt * 32 + kc, buf = st & 1;
      if (st + 1 < 64) {
        STAGE_ATTN(buf ^ 1, st + 1);
        if (w < 4) { VMCNT(5); } else { VMCNT(4); }
      } else {
        VMCNT(0);
      }
      SFENCE();
      SBAR();
      SFENCE();
      f16x8 qf[4], kf[4];
      #pragma unroll
      for (int i = 0; i < 4; ++i) {
        qf[i] = *(const f16x8*)(&Qs[buf][(i * 16 + l15) * 32 + (g ^ swz) * 8]);
        kf[i] = *(const f16x8*)(&Ks[buf][(w * 64 + i * 16 + l15) * 32 + (g ^ swz) * 8]);
      }
      __builtin_amdgcn_s_setprio(1);
      #pragma unroll
      for (int mi = 0; mi < 4; ++mi)
        #pragma unroll
        for (int ni = 0; ni < 4; ++ni)
          acc[mi][ni] = MFMA16(qf[mi], kf[ni], acc[mi][ni]);
      __builtin_amdgcn_s_setprio(0);
      SBAR();
    }
    // online softmax + fused Σp·w  (key t = t0 + tt*512 + w*64 + ni*16 + l15)
    float wvv[4];
    #pragma unroll
    for (int ni = 0; ni < 4; ++ni)
      wvv[ni] = wv[rbase + t0 + tt * 512 + w * 64 + ni * 16 + l15];
    #pragma unroll
    for (int mi = 0; mi < 4; ++mi) {
      #pragma unroll
      for (int r = 0; r < 4; ++r) {
        float v = fmaxf(fmaxf(acc[mi][0][r], acc[mi][1][r]),
                        fmaxf(acc[mi][2][r], acc[mi][3][r]));
        #pragma unroll
        for (int off = 1; off < 16; off <<= 1) v = fmaxf(v, __shfl_xor(v, off, 64));
        float mn = fmaxf(mrun[mi][r], v);
        float scl = __expf(mrun[mi][r] - mn);
        float pn = 0.f, pd = 0.f;
        #pragma unroll
        for (int ni = 0; ni < 4; ++ni) {
          float p = __expf(acc[mi][ni][r] - mn);
          pn += p * wvv[ni];
          pd += p;
        }
        num[mi][r] = num[mi][r] * scl + pn;
        den[mi][r] = den[mi][r] * scl + pd;
        mrun[mi][r] = mn;
      }
    }
  }
  // reduce partials across the 16 key-lanes of each fragment
  #pragma unroll
  for (int mi = 0; mi < 4; ++mi)
    #pragma unroll
    for (int r = 0; r < 4; ++r) {
      #pragma unroll
      for (int off = 1; off < 16; off <<= 1) {
        num[mi][r] += __shfl_xor(num[mi][r], off, 64);
        den[mi][r] += __shfl_xor(den[mi][r], off, 64);
      }
    }
  if (l15 == 0) {
    #pragma unroll
    for (int mi = 0; mi < 4; ++mi)
      #pragma unroll
      for (int r = 0; r < 4; ++r) {
        int row = mi * 16 + g * 4 + r;
        sm[0][w][row] = mrun[mi][r];
        sm[1][w][row] = num[mi][r];
        sm[2][w][row] = den[mi][r];
      }
  }
  __syncthreads();
  if (tid < 64) {
    float M = sm[0][0][tid];
    #pragma unroll
    for (int j = 1; j < 8; ++j) M = fmaxf(M, sm[0][j][tid]);
    float N = 0.f, Dn = 0.f;
    #pragma unroll
    for (int j = 0; j < 8; ++j) {
      float e = __expf(sm[0][j][tid] - M);
      N += sm[1][j][tid] * e;
      Dn += sm[2][j][tid] * e;
    }
    size_t row = rbase + q0 + tid;
    part[row * 6 + h * 3 + 0] = M;
    part[row * 6 + h * 3 + 1] = N;
    part[row * 6 + h * 3 + 2] = Dn;
  }
}

// ------------- kernel 6: merge the two key-half partials --------------------
__global__ void k_fin(const float* __restrict__ part, const float* __restrict__ bo,
                      float* __restrict__ out) {
  int idx = blockIdx.x * 256 + threadIdx.x;
  if (idx >= B_ * S_) return;
  float m1 = part[idx * 6 + 0], n1 = part[idx * 6 + 1], d1 = part[idx * 6 + 2];
  float m2 = part[idx * 6 + 3], n2 = part[idx * 6 + 4], d2 = part[idx * 6 + 5];
  float M = fmaxf(m1, m2);
  float e1 = __expf(m1 - M), e2 = __expf(m2 - M);
  out[idx] = (n1 * e1 + n2 * e2) / (d1 * e1 + d2 * e2) + bo[0];
}

extern "C" void kernel_launch(void* const* d_in, const int* in_sizes, int n_in,
                              void* d_out, int out_size, void* d_ws, size_t ws_size,
                              hipStream_t stream) {
  const float* x  = (const float*)d_in[0];
  const float* Wq = (const float*)d_in[1];
  const float* bq = (const float*)d_in[2];
  const float* Wk = (const float*)d_in[3];
  const float* bk = (const float*)d_in[4];
  const float* Wv = (const float*)d_in[5];
  const float* bv = (const float*)d_in[6];
  const float* Wo = (const float*)d_in[7];
  const float* bo = (const float*)d_in[8];
  float* out = (float*)d_out;

  char* ws = (char*)d_ws;
  h16*   xh   = (h16*)ws;                                         // 32 MB
  h16*   Wt   = (h16*)(ws + (size_t)32 * 1024 * 1024);            // 4 MB
  h16*   qkh  = (h16*)(ws + (size_t)36 * 1024 * 1024);            // 64 MB
  float* wv   = (float*)(ws + (size_t)100 * 1024 * 1024);         // 64 KB
  float* u    = (float*)(ws + (size_t)100 * 1024 * 1024 + 65536); // 4.1 KB
  float* part = (float*)(ws + (size_t)101 * 1024 * 1024);         // 384 KB

  hipLaunchKernelGGL(k_u,    dim3(257),    dim3(256),   0, stream, Wv, Wo, bv, u);
  hipLaunchKernelGGL(k_wt,   dim3(64, 32), dim3(32, 8), 0, stream, Wq, Wk, Wt);
  hipLaunchKernelGGL(k_xw,   dim3(4096),   dim3(256),   0, stream, x, u, xh, wv);
  hipLaunchKernelGGL(k_proj, dim3(2048),   dim3(256),   0, stream, xh, Wt, bq, bk, qkh);
  hipLaunchKernelGGL(k_attn, dim3(512),    dim3(512),   0, stream, qkh, wv, part);
  hipLaunchKernelGGL(k_fin,  dim3(64),     dim3(256),   0, stream, part, bo, out);
}

// Round 6
// 282.438 us; speedup vs baseline: 1.6197x; 1.1647x over previous
//
#include <hip/hip_runtime.h>
#include <stdint.h>

#define D_ 1024
#define S_ 2048
#define B_ 8

typedef _Float16 h16;
typedef _Float16 f16x8 __attribute__((ext_vector_type(8)));
typedef _Float16 f16x4 __attribute__((ext_vector_type(4)));
typedef float    f32x4 __attribute__((ext_vector_type(4)));

typedef __attribute__((address_space(3))) void lds_void;
typedef const __attribute__((address_space(1))) void g_void;

#define MFMA16(a, b, c) __builtin_amdgcn_mfma_f32_16x16x32_f16(a, b, c, 0, 0, 0)
#define VMCNT(n) asm volatile("s_waitcnt vmcnt(" #n ")" ::: "memory")
#define SFENCE() __builtin_amdgcn_sched_barrier(0)
#define SBAR() __builtin_amdgcn_s_barrier()

// Stage one 16-row x 32-half (1KB) chunk via global_load_lds (linear LDS dest).
// Swizzle (both-sides, rule #21): stored slot s' holds logical 16B col-chunk
// c = s' ^ ((row>>1)&3).  Write: lane l -> row=l>>2, slot=l&3, global chunk
// c=(l&3)^((l>>3)&3).  Read: logical chunk g at slot g ^ ((row>>1)&3).
__device__ __forceinline__ void stage16(const h16* g0, int ld, h16* lchunk) {
  int lane = threadIdx.x & 63;
  int c = (lane & 3) ^ ((lane >> 3) & 3);
  const h16* ga = g0 + (size_t)(lane >> 2) * ld + c * 8;
  __builtin_amdgcn_global_load_lds((g_void*)ga, (lds_void*)lchunk, 16, 0, 0);
}

// ------- kernel 1: u[e] = Wv[e,:]·Wo (wave per row); u[D] = bv·Wo -----------
__global__ void k_u(const float* __restrict__ Wv, const float* __restrict__ Wo,
                    const float* __restrict__ bv, float* __restrict__ u) {
  int lane = threadIdx.x & 63;
  if (blockIdx.x == 256) {            // bias block: u[D] = bv·Wo, one wave
    if (threadIdx.x < 64) {
      float s = 0.f;
      #pragma unroll
      for (int j = 0; j < 4; ++j) {
        float4 a = ((const float4*)bv)[j * 64 + lane];
        float4 b = ((const float4*)Wo)[j * 64 + lane];
        s += a.x * b.x + a.y * b.y + a.z * b.z + a.w * b.w;
      }
      #pragma unroll
      for (int off = 32; off; off >>= 1) s += __shfl_xor(s, off, 64);
      if (lane == 0) u[D_] = s;
    }
    return;
  }
  int row = blockIdx.x * 4 + (threadIdx.x >> 6);
  const float4* r4 = (const float4*)(Wv + (size_t)row * D_);
  const float4* w4 = (const float4*)Wo;
  float s = 0.f;
  #pragma unroll
  for (int j = 0; j < 4; ++j) {
    int c = j * 64 + lane;
    float4 a = r4[c], b = w4[c];
    s += a.x * b.x + a.y * b.y + a.z * b.z + a.w * b.w;
  }
  #pragma unroll
  for (int off = 32; off; off >>= 1) s += __shfl_xor(s, off, 64);
  if (lane == 0) u[row] = s;
}

// ------------- kernel 2: Wt[n][k] = (n<D ? Wq : Wk)[k][n]  (fp16) -----------
__global__ void k_wt(const float* __restrict__ Wq, const float* __restrict__ Wk,
                     h16* __restrict__ Wt) {
  __shared__ float t[32][33];
  int n0 = blockIdx.x * 32;
  int k0 = blockIdx.y * 32;
  const float* src = (n0 < D_) ? Wq : Wk;
  int nn = n0 & (D_ - 1);
  int tx = threadIdx.x, ty = threadIdx.y;
  for (int i = ty; i < 32; i += 8)
    t[i][tx] = src[(size_t)(k0 + i) * D_ + nn + tx];
  __syncthreads();
  for (int i = ty; i < 32; i += 8)
    Wt[(size_t)(n0 + i) * D_ + k0 + tx] = (h16)t[tx][i];
}

// -------- kernel 3: xh = fp16(x);  w[r] = x[r,:]·u + u[D]  (one wave/row) ---
__global__ void k_xw(const float* __restrict__ x, const float* __restrict__ u,
                     h16* __restrict__ xh, float* __restrict__ w) {
  int row = blockIdx.x * 4 + (threadIdx.x >> 6);
  int lane = threadIdx.x & 63;
  const float4* xr = (const float4*)(x + (size_t)row * D_);
  const float4* u4 = (const float4*)u;
  h16* xo = xh + (size_t)row * D_;
  float s = 0.f;
  #pragma unroll
  for (int j = 0; j < 4; ++j) {
    int c = j * 64 + lane;
    float4 a = xr[c];
    float4 b = u4[c];
    s += a.x * b.x + a.y * b.y + a.z * b.z + a.w * b.w;
    f16x4 o;
    o[0] = (h16)a.x; o[1] = (h16)a.y; o[2] = (h16)a.z; o[3] = (h16)a.w;
    *(f16x4*)(xo + c * 4) = o;
  }
  #pragma unroll
  for (int off = 32; off; off >>= 1) s += __shfl_xor(s, off, 64);
  if (lane == 0) w[row] = s + u[D_];
}

// ------ kernel 4: qkh[16384][2048] = xh·[Wq|Wk] + [bq|bk]   (fp16 out) ------
// 256x128 tile, 512 thr / 8 waves (4x2), BK=32, counted-vmcnt 2-buffer.
// Per wave per step: 2 A-chunks + 1 B-chunk = 3 stage16 -> vmcnt(3) uniform.
__global__ __launch_bounds__(512, 4) void k_proj(
    const h16* __restrict__ xh, const h16* __restrict__ Wt,
    const float* __restrict__ bq_, const float* __restrict__ bk_,
    h16* __restrict__ qkh) {
  __shared__ alignas(16) h16 As[2][256 * 32];   // 32 KB
  __shared__ alignas(16) h16 Bs[2][128 * 32];   // 16 KB
  int tid = threadIdx.x;
  int w = tid >> 6;
  int lane = tid & 63;
  int wrow = w >> 1, wcol = w & 1;
  int g = lane >> 4, l15 = lane & 15;
  int swz = (l15 >> 1) & 3;

  // XCD swizzle: 1024 blocks; XCD x owns a contiguous m-stripe, n fastest.
  int idx = (blockIdx.x & 7) * 128 + (blockIdx.x >> 3);
  int m0 = (idx >> 4) * 256, n0 = (idx & 15) * 128;

  const h16* abase0 = xh + (size_t)(m0 + (2 * w) * 16) * D_;
  const h16* abase1 = abase0 + (size_t)16 * D_;
  const h16* bbase  = Wt + (size_t)(n0 + w * 16) * D_;

  f32x4 acc[4][4] = {};

  #define STAGE_PROJ(buf, k)                                          \
    {                                                                 \
      int k0_ = (k) * 32;                                             \
      stage16(abase0 + k0_, D_, &As[buf][(2 * w) * 512]);             \
      stage16(abase1 + k0_, D_, &As[buf][(2 * w + 1) * 512]);         \
      stage16(bbase + k0_, D_, &Bs[buf][w * 512]);                    \
    }

  STAGE_PROJ(0, 0);
  #pragma unroll 2
  for (int k = 0; k < 32; ++k) {
    int buf = k & 1;
    if (k + 1 < 32) {
      STAGE_PROJ(buf ^ 1, k + 1);
      VMCNT(3);
    } else {
      VMCNT(0);
    }
    SFENCE();
    SBAR();
    SFENCE();
    f16x8 af[4], bf[4];
    #pragma unroll
    for (int i = 0; i < 4; ++i) {
      af[i] = *(const f16x8*)(&As[buf][(wrow * 64 + i * 16 + l15) * 32 + (g ^ swz) * 8]);
      bf[i] = *(const f16x8*)(&Bs[buf][(wcol * 64 + i * 16 + l15) * 32 + (g ^ swz) * 8]);
    }
    __builtin_amdgcn_s_setprio(1);
    #pragma unroll
    for (int mi = 0; mi < 4; ++mi)
      #pragma unroll
      for (int ni = 0; ni < 4; ++ni)
        acc[mi][ni] = MFMA16(af[mi], bf[ni], acc[mi][ni]);
    __builtin_amdgcn_s_setprio(0);
    SBAR();
  }

  #pragma unroll
  for (int ni = 0; ni < 4; ++ni) {
    int n = n0 + wcol * 64 + ni * 16 + l15;
    float bias = (n < D_) ? bq_[n] : bk_[n - D_];
    #pragma unroll
    for (int mi = 0; mi < 4; ++mi) {
      #pragma unroll
      for (int r = 0; r < 4; ++r) {
        int m = m0 + wrow * 64 + mi * 16 + g * 4 + r;
        qkh[(size_t)m * (2 * D_) + n] = (h16)(acc[mi][ni][r] + bias);
      }
    }
  }
}

// -- kernel 5: scores block 128q x 256k, full-depth GEMM then ONE softmax ----
// 1024 blocks (2/CU): b=blk&7 (XCD), r=blk>>3, kc=r>>4 (dispatch-slow -> kc
// groups co-resident per XCD, K hot set 2MB L2-fit), q0=(r&15)*128.
// Per wave per step: 1 Q-chunk + 2 K-chunks = 3 stage16 -> vmcnt(3) uniform.
// acc holds the FULL 64q x 64k score tile per wave -> softmax once, no
// online state in the hot loop.  Writes (m,num,den) partial per (row, kc).
__global__ __launch_bounds__(512, 4) void k_attn(
    const h16* __restrict__ qkh, const float* __restrict__ wv,
    float* __restrict__ part) {
  __shared__ alignas(16) h16 Qs[2][128 * 32];   // 16 KB
  __shared__ alignas(16) h16 Ks[2][256 * 32];   // 32 KB
  __shared__ float sm[3][4][128];               // 6 KB
  int tid = threadIdx.x;
  int w = tid >> 6;
  int lane = tid & 63;
  int g = lane >> 4, l15 = lane & 15;
  int swz = (l15 >> 1) & 3;
  int wq = w >> 2, wkc = w & 3;                  // wave: 64q x 64k sub-tile
  int b = blockIdx.x & 7;
  int r = blockIdx.x >> 3;
  int kc = r >> 4;
  int q0 = (r & 15) * 128;
  size_t rbase = (size_t)b * S_;

  const h16* qbase  = qkh + (rbase + q0 + w * 16) * (2 * D_);
  const h16* kbase0 = qkh + (rbase + kc * 256 + (2 * w) * 16) * (2 * D_) + D_;
  const h16* kbase1 = kbase0 + (size_t)16 * (2 * D_);

  #define STAGE_ATTN(buf, st)                                         \
    {                                                                 \
      int k0_ = (st) * 32;                                            \
      stage16(qbase + k0_, 2 * D_, &Qs[buf][w * 512]);                \
      stage16(kbase0 + k0_, 2 * D_, &Ks[buf][(2 * w) * 512]);         \
      stage16(kbase1 + k0_, 2 * D_, &Ks[buf][(2 * w + 1) * 512]);     \
    }

  f32x4 acc[4][4] = {};

  STAGE_ATTN(0, 0);
  #pragma unroll 2
  for (int st = 0; st < 32; ++st) {
    int buf = st & 1;
    if (st + 1 < 32) {
      STAGE_ATTN(buf ^ 1, st + 1);
      VMCNT(3);
    } else {
      VMCNT(0);
    }
    SFENCE();
    SBAR();
    SFENCE();
    f16x8 qf[4], kf[4];
    #pragma unroll
    for (int i = 0; i < 4; ++i) {
      qf[i] = *(const f16x8*)(&Qs[buf][(wq * 64 + i * 16 + l15) * 32 + (g ^ swz) * 8]);
      kf[i] = *(const f16x8*)(&Ks[buf][(wkc * 64 + i * 16 + l15) * 32 + (g ^ swz) * 8]);
    }
    __builtin_amdgcn_s_setprio(1);
    #pragma unroll
    for (int mi = 0; mi < 4; ++mi)
      #pragma unroll
      for (int ni = 0; ni < 4; ++ni)
        acc[mi][ni] = MFMA16(qf[mi], kf[ni], acc[mi][ni]);
    __builtin_amdgcn_s_setprio(0);
    SBAR();
  }

  // ---- softmax partial over this block's 256 keys (once, post-loop) ----
  float wvv[4];
  #pragma unroll
  for (int ni = 0; ni < 4; ++ni)
    wvv[ni] = wv[rbase + kc * 256 + wkc * 64 + ni * 16 + l15];
  #pragma unroll
  for (int mi = 0; mi < 4; ++mi) {
    #pragma unroll
    for (int rr = 0; rr < 4; ++rr) {
      float v = fmaxf(fmaxf(acc[mi][0][rr], acc[mi][1][rr]),
                      fmaxf(acc[mi][2][rr], acc[mi][3][rr]));
      #pragma unroll
      for (int off = 1; off < 16; off <<= 1) v = fmaxf(v, __shfl_xor(v, off, 64));
      float pn = 0.f, pd = 0.f;
      #pragma unroll
      for (int ni = 0; ni < 4; ++ni) {
        float p = __expf(acc[mi][ni][rr] - v);
        pn += p * wvv[ni];
        pd += p;
      }
      #pragma unroll
      for (int off = 1; off < 16; off <<= 1) {
        pn += __shfl_xor(pn, off, 64);
        pd += __shfl_xor(pd, off, 64);
      }
      if (l15 == 0) {
        int row = wq * 64 + mi * 16 + g * 4 + rr;
        sm[0][wkc][row] = v;
        sm[1][wkc][row] = pn;
        sm[2][wkc][row] = pd;
      }
    }
  }
  __syncthreads();
  if (tid < 128) {
    float M = sm[0][0][tid];
    #pragma unroll
    for (int j = 1; j < 4; ++j) M = fmaxf(M, sm[0][j][tid]);
    float N = 0.f, Dn = 0.f;
    #pragma unroll
    for (int j = 0; j < 4; ++j) {
      float e = __expf(sm[0][j][tid] - M);
      N += sm[1][j][tid] * e;
      Dn += sm[2][j][tid] * e;
    }
    size_t row = rbase + q0 + tid;
    part[row * 24 + kc * 3 + 0] = M;
    part[row * 24 + kc * 3 + 1] = N;
    part[row * 24 + kc * 3 + 2] = Dn;
  }
}

// ------------- kernel 6: merge the 8 key-chunk partials ---------------------
__global__ void k_fin(const float* __restrict__ part, const float* __restrict__ bo,
                      float* __restrict__ out) {
  int idx = blockIdx.x * 256 + threadIdx.x;
  if (idx >= B_ * S_) return;
  const float* p = part + (size_t)idx * 24;
  float M = p[0];
  #pragma unroll
  for (int j = 1; j < 8; ++j) M = fmaxf(M, p[j * 3]);
  float N = 0.f, Dn = 0.f;
  #pragma unroll
  for (int j = 0; j < 8; ++j) {
    float e = __expf(p[j * 3] - M);
    N += p[j * 3 + 1] * e;
    Dn += p[j * 3 + 2] * e;
  }
  out[idx] = N / Dn + bo[0];
}

extern "C" void kernel_launch(void* const* d_in, const int* in_sizes, int n_in,
                              void* d_out, int out_size, void* d_ws, size_t ws_size,
                              hipStream_t stream) {
  const float* x  = (const float*)d_in[0];
  const float* Wq = (const float*)d_in[1];
  const float* bq = (const float*)d_in[2];
  const float* Wk = (const float*)d_in[3];
  const float* bk = (const float*)d_in[4];
  const float* Wv = (const float*)d_in[5];
  const float* bv = (const float*)d_in[6];
  const float* Wo = (const float*)d_in[7];
  const float* bo = (const float*)d_in[8];
  float* out = (float*)d_out;

  char* ws = (char*)d_ws;
  h16*   xh   = (h16*)ws;                                         // 32 MB
  h16*   Wt   = (h16*)(ws + (size_t)32 * 1024 * 1024);            // 4 MB
  h16*   qkh  = (h16*)(ws + (size_t)36 * 1024 * 1024);            // 64 MB
  float* wv   = (float*)(ws + (size_t)100 * 1024 * 1024);         // 64 KB
  float* u    = (float*)(ws + (size_t)100 * 1024 * 1024 + 65536); // 4.1 KB
  float* part = (float*)(ws + (size_t)101 * 1024 * 1024);         // 1.5 MB

  hipLaunchKernelGGL(k_u,    dim3(257),    dim3(256),   0, stream, Wv, Wo, bv, u);
  hipLaunchKernelGGL(k_wt,   dim3(64, 32), dim3(32, 8), 0, stream, Wq, Wk, Wt);
  hipLaunchKernelGGL(k_xw,   dim3(4096),   dim3(256),   0, stream, x, u, xh, wv);
  hipLaunchKernelGGL(k_proj, dim3(1024),   dim3(512),   0, stream, xh, Wt, bq, bk, qkh);
  hipLaunchKernelGGL(k_attn, dim3(1024),   dim3(512),   0, stream, qkh, wv, part);
  hipLaunchKernelGGL(k_fin,  dim3(64),     dim3(256),   0, stream, part, bo, out);
}

// Round 8
// 280.088 us; speedup vs baseline: 1.6332x; 1.0084x over previous
//
#include <hip/hip_runtime.h>
#include <stdint.h>

#define D_ 1024
#define S_ 2048
#define B_ 8

typedef _Float16 h16;
typedef _Float16 f16x8 __attribute__((ext_vector_type(8)));
typedef _Float16 f16x4 __attribute__((ext_vector_type(4)));
typedef float    f32x4 __attribute__((ext_vector_type(4)));

typedef __attribute__((address_space(3))) void lds_void;
typedef const __attribute__((address_space(1))) void g_void;

#define MFMA16(a, b, c) __builtin_amdgcn_mfma_f32_16x16x32_f16(a, b, c, 0, 0, 0)
#define VMCNT(n) asm volatile("s_waitcnt vmcnt(" #n ")" ::: "memory")
#define SFENCE() __builtin_amdgcn_sched_barrier(0)
#define SBAR() __builtin_amdgcn_s_barrier()

// Stage one 16-row x 32-half (1KB) chunk via global_load_lds (linear LDS dest).
// Swizzle (both-sides, rule #21): stored slot s' holds logical 16B col-chunk
// c = s' ^ ((row>>1)&3).  Write: lane l -> row=l>>2, slot=l&3, global chunk
// c=(l&3)^((l>>3)&3).  Read: logical chunk g at slot g ^ ((row>>1)&3).
__device__ __forceinline__ void stage16(const h16* g0, int ld, h16* lchunk) {
  int lane = threadIdx.x & 63;
  int c = (lane & 3) ^ ((lane >> 3) & 3);
  const h16* ga = g0 + (size_t)(lane >> 2) * ld + c * 8;
  __builtin_amdgcn_global_load_lds((g_void*)ga, (lds_void*)lchunk, 16, 0, 0);
}

// ------- kernel 1: u[e] = Wv[e,:]·Wo (wave per row); u[D] = bv·Wo -----------
__global__ void k_u(const float* __restrict__ Wv, const float* __restrict__ Wo,
                    const float* __restrict__ bv, float* __restrict__ u) {
  int lane = threadIdx.x & 63;
  if (blockIdx.x == 256) {            // bias block: u[D] = bv·Wo, one wave
    if (threadIdx.x < 64) {
      float s = 0.f;
      #pragma unroll
      for (int j = 0; j < 4; ++j) {
        float4 a = ((const float4*)bv)[j * 64 + lane];
        float4 b = ((const float4*)Wo)[j * 64 + lane];
        s += a.x * b.x + a.y * b.y + a.z * b.z + a.w * b.w;
      }
      #pragma unroll
      for (int off = 32; off; off >>= 1) s += __shfl_xor(s, off, 64);
      if (lane == 0) u[D_] = s;
    }
    return;
  }
  int row = blockIdx.x * 4 + (threadIdx.x >> 6);
  const float4* r4 = (const float4*)(Wv + (size_t)row * D_);
  const float4* w4 = (const float4*)Wo;
  float s = 0.f;
  #pragma unroll
  for (int j = 0; j < 4; ++j) {
    int c = j * 64 + lane;
    float4 a = r4[c], b = w4[c];
    s += a.x * b.x + a.y * b.y + a.z * b.z + a.w * b.w;
  }
  #pragma unroll
  for (int off = 32; off; off >>= 1) s += __shfl_xor(s, off, 64);
  if (lane == 0) u[row] = s;
}

// ------------- kernel 2: Wt[n][k] = (n<D ? Wq : Wk)[k][n]  (fp16) -----------
__global__ void k_wt(const float* __restrict__ Wq, const float* __restrict__ Wk,
                     h16* __restrict__ Wt) {
  __shared__ float t[32][33];
  int n0 = blockIdx.x * 32;
  int k0 = blockIdx.y * 32;
  const float* src = (n0 < D_) ? Wq : Wk;
  int nn = n0 & (D_ - 1);
  int tx = threadIdx.x, ty = threadIdx.y;
  for (int i = ty; i < 32; i += 8)
    t[i][tx] = src[(size_t)(k0 + i) * D_ + nn + tx];
  __syncthreads();
  for (int i = ty; i < 32; i += 8)
    Wt[(size_t)(n0 + i) * D_ + k0 + tx] = (h16)t[tx][i];
}

// -------- kernel 3: xh = fp16(x);  w[r] = x[r,:]·u + u[D]  (one wave/row) ---
__global__ void k_xw(const float* __restrict__ x, const float* __restrict__ u,
                     h16* __restrict__ xh, float* __restrict__ w) {
  int row = blockIdx.x * 4 + (threadIdx.x >> 6);
  int lane = threadIdx.x & 63;
  const float4* xr = (const float4*)(x + (size_t)row * D_);
  const float4* u4 = (const float4*)u;
  h16* xo = xh + (size_t)row * D_;
  float s = 0.f;
  #pragma unroll
  for (int j = 0; j < 4; ++j) {
    int c = j * 64 + lane;
    float4 a = xr[c];
    float4 b = u4[c];
    s += a.x * b.x + a.y * b.y + a.z * b.z + a.w * b.w;
    f16x4 o;
    o[0] = (h16)a.x; o[1] = (h16)a.y; o[2] = (h16)a.z; o[3] = (h16)a.w;
    *(f16x4*)(xo + c * 4) = o;
  }
  #pragma unroll
  for (int off = 32; off; off >>= 1) s += __shfl_xor(s, off, 64);
  if (lane == 0) w[row] = s + u[D_];
}

// ------ kernel 4: qkh[16384][2048] = xh·[Wq|Wk] + [bq|bk]   (fp16 out) ------
// 256x128 tile, 512 thr / 8 waves (4x2), BK=32, 3-buffer 2-step-lookahead
// counted-vmcnt schedule: stage st+2, wait vmcnt(6) (two younger 3-load
// groups in flight), raw barriers, drain 3->0 in last two iters.
__global__ __launch_bounds__(512, 4) void k_proj(
    const h16* __restrict__ xh, const h16* __restrict__ Wt,
    const float* __restrict__ bq_, const float* __restrict__ bk_,
    h16* __restrict__ qkh) {
  __shared__ alignas(16) h16 As[3][256 * 32];   // 48 KB
  __shared__ alignas(16) h16 Bs[3][128 * 32];   // 24 KB
  int tid = threadIdx.x;
  int w = tid >> 6;
  int lane = tid & 63;
  int wrow = w >> 1, wcol = w & 1;
  int g = lane >> 4, l15 = lane & 15;
  int swz = (l15 >> 1) & 3;

  // XCD swizzle: 1024 blocks; XCD x owns a contiguous m-stripe, n fastest.
  int idx = (blockIdx.x & 7) * 128 + (blockIdx.x >> 3);
  int m0 = (idx >> 4) * 256, n0 = (idx & 15) * 128;

  const h16* abase0 = xh + (size_t)(m0 + (2 * w) * 16) * D_;
  const h16* abase1 = abase0 + (size_t)16 * D_;
  const h16* bbase  = Wt + (size_t)(n0 + w * 16) * D_;

  f32x4 acc[4][4] = {};

  #define STAGE_PROJ(ap, bp, k)                              \
    {                                                        \
      int k0_ = (k) * 32;                                    \
      stage16(abase0 + k0_, D_, (ap) + (2 * w) * 512);       \
      stage16(abase1 + k0_, D_, (ap) + (2 * w + 1) * 512);   \
      stage16(bbase + k0_, D_, (bp) + w * 512);              \
    }

  h16 *A0 = As[0], *A1 = As[1], *A2 = As[2];
  h16 *B0 = Bs[0], *B1 = Bs[1], *B2 = Bs[2];
  STAGE_PROJ(A0, B0, 0);
  STAGE_PROJ(A1, B1, 1);
  for (int k = 0; k < 32; ++k) {
    if (k + 2 < 32) {
      STAGE_PROJ(A2, B2, k + 2);
      VMCNT(6);
    } else if (k + 1 < 32) {
      VMCNT(3);
    } else {
      VMCNT(0);
    }
    SFENCE();
    SBAR();
    SFENCE();
    f16x8 af[4], bf[4];
    #pragma unroll
    for (int i = 0; i < 4; ++i) {
      af[i] = *(const f16x8*)(A0 + (wrow * 64 + i * 16 + l15) * 32 + (g ^ swz) * 8);
      bf[i] = *(const f16x8*)(B0 + (wcol * 64 + i * 16 + l15) * 32 + (g ^ swz) * 8);
    }
    __builtin_amdgcn_s_setprio(1);
    #pragma unroll
    for (int mi = 0; mi < 4; ++mi)
      #pragma unroll
      for (int ni = 0; ni < 4; ++ni)
        acc[mi][ni] = MFMA16(af[mi], bf[ni], acc[mi][ni]);
    __builtin_amdgcn_s_setprio(0);
    SBAR();
    h16* t;
    t = A0; A0 = A1; A1 = A2; A2 = t;
    t = B0; B0 = B1; B1 = B2; B2 = t;
  }

  #pragma unroll
  for (int ni = 0; ni < 4; ++ni) {
    int n = n0 + wcol * 64 + ni * 16 + l15;
    float bias = (n < D_) ? bq_[n] : bk_[n - D_];
    #pragma unroll
    for (int mi = 0; mi < 4; ++mi) {
      #pragma unroll
      for (int r = 0; r < 4; ++r) {
        int m = m0 + wrow * 64 + mi * 16 + g * 4 + r;
        qkh[(size_t)m * (2 * D_) + n] = (h16)(acc[mi][ni][r] + bias);
      }
    }
  }
}

// -- kernel 5: scores block 128q x 256k, full-depth GEMM then ONE softmax ----
// 1024 blocks (2/CU). 3-buffer 2-step-lookahead counted-vmcnt schedule.
// Per wave per step: 1 Q-chunk + 2 K-chunks = 3 stage16 (uniform).
__global__ __launch_bounds__(512, 4) void k_attn(
    const h16* __restrict__ qkh, const float* __restrict__ wv,
    float* __restrict__ part) {
  __shared__ alignas(16) h16 Qs[3][128 * 32];   // 24 KB
  __shared__ alignas(16) h16 Ks[3][256 * 32];   // 48 KB
  __shared__ float sm[3][4][128];               // 6 KB
  int tid = threadIdx.x;
  int w = tid >> 6;
  int lane = tid & 63;
  int g = lane >> 4, l15 = lane & 15;
  int swz = (l15 >> 1) & 3;
  int wq = w >> 2, wkc = w & 3;                  // wave: 64q x 64k sub-tile
  int b = blockIdx.x & 7;
  int r = blockIdx.x >> 3;
  int kc = r >> 4;
  int q0 = (r & 15) * 128;
  size_t rbase = (size_t)b * S_;

  const h16* qbase  = qkh + (rbase + q0 + w * 16) * (2 * D_);
  const h16* kbase0 = qkh + (rbase + kc * 256 + (2 * w) * 16) * (2 * D_) + D_;
  const h16* kbase1 = kbase0 + (size_t)16 * (2 * D_);

  #define STAGE_ATTN(qp, kp, st)                             \
    {                                                        \
      int k0_ = (st) * 32;                                   \
      stage16(qbase + k0_, 2 * D_, (qp) + w * 512);          \
      stage16(kbase0 + k0_, 2 * D_, (kp) + (2 * w) * 512);   \
      stage16(kbase1 + k0_, 2 * D_, (kp) + (2 * w + 1) * 512); \
    }

  f32x4 acc[4][4] = {};

  h16 *Q0 = Qs[0], *Q1 = Qs[1], *Q2 = Qs[2];
  h16 *K0 = Ks[0], *K1 = Ks[1], *K2 = Ks[2];
  STAGE_ATTN(Q0, K0, 0);
  STAGE_ATTN(Q1, K1, 1);
  for (int st = 0; st < 32; ++st) {
    if (st + 2 < 32) {
      STAGE_ATTN(Q2, K2, st + 2);
      VMCNT(6);
    } else if (st + 1 < 32) {
      VMCNT(3);
    } else {
      VMCNT(0);
    }
    SFENCE();
    SBAR();
    SFENCE();
    f16x8 qf[4], kf[4];
    #pragma unroll
    for (int i = 0; i < 4; ++i) {
      qf[i] = *(const f16x8*)(Q0 + (wq * 64 + i * 16 + l15) * 32 + (g ^ swz) * 8);
      kf[i] = *(const f16x8*)(K0 + (wkc * 64 + i * 16 + l15) * 32 + (g ^ swz) * 8);
    }
    __builtin_amdgcn_s_setprio(1);
    #pragma unroll
    for (int mi = 0; mi < 4; ++mi)
      #pragma unroll
      for (int ni = 0; ni < 4; ++ni)
        acc[mi][ni] = MFMA16(qf[mi], kf[ni], acc[mi][ni]);
    __builtin_amdgcn_s_setprio(0);
    SBAR();
    h16* t;
    t = Q0; Q0 = Q1; Q1 = Q2; Q2 = t;
    t = K0; K0 = K1; K1 = K2; K2 = t;
  }

  // ---- softmax partial over this block's 256 keys (once, post-loop) ----
  float wvv[4];
  #pragma unroll
  for (int ni = 0; ni < 4; ++ni)
    wvv[ni] = wv[rbase + kc * 256 + wkc * 64 + ni * 16 + l15];
  #pragma unroll
  for (int mi = 0; mi < 4; ++mi) {
    #pragma unroll
    for (int rr = 0; rr < 4; ++rr) {
      float v = fmaxf(fmaxf(acc[mi][0][rr], acc[mi][1][rr]),
                      fmaxf(acc[mi][2][rr], acc[mi][3][rr]));
      #pragma unroll
      for (int off = 1; off < 16; off <<= 1) v = fmaxf(v, __shfl_xor(v, off, 64));
      float pn = 0.f, pd = 0.f;
      #pragma unroll
      for (int ni = 0; ni < 4; ++ni) {
        float p = __expf(acc[mi][ni][rr] - v);
        pn += p * wvv[ni];
        pd += p;
      }
      #pragma unroll
      for (int off = 1; off < 16; off <<= 1) {
        pn += __shfl_xor(pn, off, 64);
        pd += __shfl_xor(pd, off, 64);
      }
      if (l15 == 0) {
        int row = wq * 64 + mi * 16 + g * 4 + rr;
        sm[0][wkc][row] = v;
        sm[1][wkc][row] = pn;
        sm[2][wkc][row] = pd;
      }
    }
  }
  __syncthreads();
  if (tid < 128) {
    float M = sm[0][0][tid];
    #pragma unroll
    for (int j = 1; j < 4; ++j) M = fmaxf(M, sm[0][j][tid]);
    float N = 0.f, Dn = 0.f;
    #pragma unroll
    for (int j = 0; j < 4; ++j) {
      float e = __expf(sm[0][j][tid] - M);
      N += sm[1][j][tid] * e;
      Dn += sm[2][j][tid] * e;
    }
    size_t row = rbase + q0 + tid;
    part[row * 24 + kc * 3 + 0] = M;
    part[row * 24 + kc * 3 + 1] = N;
    part[row * 24 + kc * 3 + 2] = Dn;
  }
}

// ------------- kernel 6: merge the 8 key-chunk partials ---------------------
__global__ void k_fin(const float* __restrict__ part, const float* __restrict__ bo,
                      float* __restrict__ out) {
  int idx = blockIdx.x * 256 + threadIdx.x;
  if (idx >= B_ * S_) return;
  const float* p = part + (size_t)idx * 24;
  float M = p[0];
  #pragma unroll
  for (int j = 1; j < 8; ++j) M = fmaxf(M, p[j * 3]);
  float N = 0.f, Dn = 0.f;
  #pragma unroll
  for (int j = 0; j < 8; ++j) {
    float e = __expf(p[j * 3] - M);
    N += p[j * 3 + 1] * e;
    Dn += p[j * 3 + 2] * e;
  }
  out[idx] = N / Dn + bo[0];
}

extern "C" void kernel_launch(void* const* d_in, const int* in_sizes, int n_in,
                              void* d_out, int out_size, void* d_ws, size_t ws_size,
                              hipStream_t stream) {
  const float* x  = (const float*)d_in[0];
  const float* Wq = (const float*)d_in[1];
  const float* bq = (const float*)d_in[2];
  const float* Wk = (const float*)d_in[3];
  const float* bk = (const float*)d_in[4];
  const float* Wv = (const float*)d_in[5];
  const float* bv = (const float*)d_in[6];
  const float* Wo = (const float*)d_in[7];
  const float* bo = (const float*)d_in[8];
  float* out = (float*)d_out;

  char* ws = (char*)d_ws;
  h16*   xh   = (h16*)ws;                                         // 32 MB
  h16*   Wt   = (h16*)(ws + (size_t)32 * 1024 * 1024);            // 4 MB
  h16*   qkh  = (h16*)(ws + (size_t)36 * 1024 * 1024);            // 64 MB
  float* wv   = (float*)(ws + (size_t)100 * 1024 * 1024);         // 64 KB
  float* u    = (float*)(ws + (size_t)100 * 1024 * 1024 + 65536); // 4.1 KB
  float* part = (float*)(ws + (size_t)101 * 1024 * 1024);         // 1.5 MB

  hipLaunchKernelGGL(k_u,    dim3(257),    dim3(256),   0, stream, Wv, Wo, bv, u);
  hipLaunchKernelGGL(k_wt,   dim3(64, 32), dim3(32, 8), 0, stream, Wq, Wk, Wt);
  hipLaunchKernelGGL(k_xw,   dim3(4096),   dim3(256),   0, stream, x, u, xh, wv);
  hipLaunchKernelGGL(k_proj, dim3(1024),   dim3(512),   0, stream, xh, Wt, bq, bk, qkh);
  hipLaunchKernelGGL(k_attn, dim3(1024),   dim3(512),   0, stream, qkh, wv, part);
  hipLaunchKernelGGL(k_fin,  dim3(64),     dim3(256),   0, stream, part, bo, out);
}

// Round 9
// 269.002 us; speedup vs baseline: 1.7006x; 1.0412x over previous
//
#include <hip/hip_runtime.h>
#include <stdint.h>

#define D_ 1024
#define S_ 2048
#define B_ 8

typedef _Float16 h16;
typedef _Float16 f16x8 __attribute__((ext_vector_type(8)));
typedef _Float16 f16x4 __attribute__((ext_vector_type(4)));
typedef float    f32x4 __attribute__((ext_vector_type(4)));

typedef __attribute__((address_space(3))) void lds_void;
typedef const __attribute__((address_space(1))) void g_void;

#define MFMA16(a, b, c) __builtin_amdgcn_mfma_f32_16x16x32_f16(a, b, c, 0, 0, 0)
#define VMCNT(n) asm volatile("s_waitcnt vmcnt(" #n ")" ::: "memory")
#define SFENCE() __builtin_amdgcn_sched_barrier(0)
#define SBAR() __builtin_amdgcn_s_barrier()

// Stage one 16-row x 32-half (1KB) chunk via global_load_lds (linear LDS dest).
// Swizzle (both-sides, rule #21): stored slot s' holds logical 16B col-chunk
// c = s' ^ ((row>>1)&3).  Write: lane l -> row=l>>2, slot=l&3, global chunk
// c=(l&3)^((l>>3)&3).  Read: logical chunk g at slot g ^ ((row>>1)&3).
__device__ __forceinline__ void stage16(const h16* g0, int ld, h16* lchunk) {
  int lane = threadIdx.x & 63;
  int c = (lane & 3) ^ ((lane >> 3) & 3);
  const h16* ga = g0 + (size_t)(lane >> 2) * ld + c * 8;
  __builtin_amdgcn_global_load_lds((g_void*)ga, (lds_void*)lchunk, 16, 0, 0);
}

// ---------------- kernel 0: fp16 casts of Wq, Wk ----------------------------
__global__ void k_cast(const float* __restrict__ Wq, const float* __restrict__ Wk,
                       h16* __restrict__ Wqh, h16* __restrict__ Wkh) {
  int i = blockIdx.x * 256 + threadIdx.x;
  const int n4 = (D_ * D_) / 4;
  const float4* src;
  h16* dst;
  if (i < n4) { src = (const float4*)Wq; dst = Wqh; }
  else        { src = (const float4*)Wk; dst = Wkh; i -= n4; }
  float4 a = src[i];
  f16x4 o;
  o[0] = (h16)a.x; o[1] = (h16)a.y; o[2] = (h16)a.z; o[3] = (h16)a.w;
  *(f16x4*)(dst + (size_t)i * 4) = o;
}

// -- kernel 1: u[e]=Wv[e,:]·Wo ; v2[e]=Wk[e,:]·bq ; u[D]=bv·Wo (wave/row) ----
__global__ void k_u(const float* __restrict__ Wv, const float* __restrict__ Wk,
                    const float* __restrict__ Wo, const float* __restrict__ bq_,
                    const float* __restrict__ bv, float* __restrict__ u,
                    float* __restrict__ v2) {
  int lane = threadIdx.x & 63;
  if (blockIdx.x == 256) {            // bias block: u[D] = bv·Wo, one wave
    if (threadIdx.x < 64) {
      float s = 0.f;
      #pragma unroll
      for (int j = 0; j < 4; ++j) {
        float4 a = ((const float4*)bv)[j * 64 + lane];
        float4 b = ((const float4*)Wo)[j * 64 + lane];
        s += a.x * b.x + a.y * b.y + a.z * b.z + a.w * b.w;
      }
      #pragma unroll
      for (int off = 32; off; off >>= 1) s += __shfl_xor(s, off, 64);
      if (lane == 0) u[D_] = s;
    }
    return;
  }
  int row = blockIdx.x * 4 + (threadIdx.x >> 6);
  const float4* rv = (const float4*)(Wv + (size_t)row * D_);
  const float4* rk = (const float4*)(Wk + (size_t)row * D_);
  const float4* w4 = (const float4*)Wo;
  const float4* b4 = (const float4*)bq_;
  float s1 = 0.f, s2 = 0.f;
  #pragma unroll
  for (int j = 0; j < 4; ++j) {
    int c = j * 64 + lane;
    float4 a = rv[c], b = w4[c];
    s1 += a.x * b.x + a.y * b.y + a.z * b.z + a.w * b.w;
    float4 e = rk[c], f = b4[c];
    s2 += e.x * f.x + e.y * f.y + e.z * f.z + e.w * f.w;
  }
  #pragma unroll
  for (int off = 32; off; off >>= 1) {
    s1 += __shfl_xor(s1, off, 64);
    s2 += __shfl_xor(s2, off, 64);
  }
  if (lane == 0) { u[row] = s1; v2[row] = s2; }
}

// - kernel 2: xh=fp16(x); w[r]=x·u+u[D]; c[r]=x·v2  (one wave per row) -------
__global__ void k_xw(const float* __restrict__ x, const float* __restrict__ u,
                     const float* __restrict__ v2, h16* __restrict__ xh,
                     float* __restrict__ w, float* __restrict__ cv) {
  int row = blockIdx.x * 4 + (threadIdx.x >> 6);
  int lane = threadIdx.x & 63;
  const float4* xr = (const float4*)(x + (size_t)row * D_);
  const float4* u4 = (const float4*)u;
  const float4* c4 = (const float4*)v2;
  h16* xo = xh + (size_t)row * D_;
  float s1 = 0.f, s2 = 0.f;
  #pragma unroll
  for (int j = 0; j < 4; ++j) {
    int c = j * 64 + lane;
    float4 a = xr[c];
    float4 b = u4[c];
    float4 e = c4[c];
    s1 += a.x * b.x + a.y * b.y + a.z * b.z + a.w * b.w;
    s2 += a.x * e.x + a.y * e.y + a.z * e.z + a.w * e.w;
    f16x4 o;
    o[0] = (h16)a.x; o[1] = (h16)a.y; o[2] = (h16)a.z; o[3] = (h16)a.w;
    *(f16x4*)(xo + c * 4) = o;
  }
  #pragma unroll
  for (int off = 32; off; off >>= 1) {
    s1 += __shfl_xor(s1, off, 64);
    s2 += __shfl_xor(s2, off, 64);
  }
  if (lane == 0) { w[row] = s1 + u[D_]; cv[row] = s2; }
}

// -- kernel 3: Mt[e][d] = sum_d' Wkh[e][d'] Wqh[d][d']  (128x128 tiles) ------
// 64 blocks, 256 thr / 4 waves (2x2). 3-buffer counted-vmcnt schedule,
// 4 loads/wave/step -> steady vmcnt(8), tail 4, 0.
__global__ __launch_bounds__(256, 4) void k_mt(
    const h16* __restrict__ Wkh, const h16* __restrict__ Wqh,
    h16* __restrict__ Mt) {
  __shared__ alignas(16) h16 As[3][128 * 32];
  __shared__ alignas(16) h16 Bs[3][128 * 32];
  int tid = threadIdx.x;
  int w = tid >> 6, lane = tid & 63;
  int wr = w >> 1, wc = w & 1;
  int g = lane >> 4, l15 = lane & 15;
  int swz = (l15 >> 1) & 3;
  int m0 = (blockIdx.x >> 3) * 128, n0 = (blockIdx.x & 7) * 128;

  const h16* abase0 = Wkh + (size_t)(m0 + (2 * w) * 16) * D_;
  const h16* abase1 = abase0 + (size_t)16 * D_;
  const h16* bbase0 = Wqh + (size_t)(n0 + (2 * w) * 16) * D_;
  const h16* bbase1 = bbase0 + (size_t)16 * D_;

  f32x4 acc[4][4] = {};

  #define STAGE_MT(ap, bp, k)                                \
    {                                                        \
      int k0_ = (k) * 32;                                    \
      stage16(abase0 + k0_, D_, (ap) + (2 * w) * 512);       \
      stage16(abase1 + k0_, D_, (ap) + (2 * w + 1) * 512);   \
      stage16(bbase0 + k0_, D_, (bp) + (2 * w) * 512);       \
      stage16(bbase1 + k0_, D_, (bp) + (2 * w + 1) * 512);   \
    }

  h16 *A0 = As[0], *A1 = As[1], *A2 = As[2];
  h16 *B0 = Bs[0], *B1 = Bs[1], *B2 = Bs[2];
  STAGE_MT(A0, B0, 0);
  STAGE_MT(A1, B1, 1);
  for (int k = 0; k < 32; ++k) {
    if (k + 2 < 32) {
      STAGE_MT(A2, B2, k + 2);
      VMCNT(8);
    } else if (k + 1 < 32) {
      VMCNT(4);
    } else {
      VMCNT(0);
    }
    SFENCE();
    SBAR();
    SFENCE();
    f16x8 af[4], bf[4];
    #pragma unroll
    for (int i = 0; i < 4; ++i) {
      af[i] = *(const f16x8*)(A0 + (wr * 64 + i * 16 + l15) * 32 + (g ^ swz) * 8);
      bf[i] = *(const f16x8*)(B0 + (wc * 64 + i * 16 + l15) * 32 + (g ^ swz) * 8);
    }
    __builtin_amdgcn_s_setprio(1);
    #pragma unroll
    for (int mi = 0; mi < 4; ++mi)
      #pragma unroll
      for (int ni = 0; ni < 4; ++ni)
        acc[mi][ni] = MFMA16(af[mi], bf[ni], acc[mi][ni]);
    __builtin_amdgcn_s_setprio(0);
    SBAR();
    h16* t;
    t = A0; A0 = A1; A1 = A2; A2 = t;
    t = B0; B0 = B1; B1 = B2; B2 = t;
  }

  #pragma unroll
  for (int ni = 0; ni < 4; ++ni) {
    int n = n0 + wc * 64 + ni * 16 + l15;
    #pragma unroll
    for (int mi = 0; mi < 4; ++mi) {
      #pragma unroll
      for (int r = 0; r < 4; ++r) {
        int m = m0 + wr * 64 + mi * 16 + g * 4 + r;
        Mt[(size_t)m * D_ + n] = (h16)(acc[mi][ni][r]);
      }
    }
  }
}

// ------ kernel 4: y[16384][1024] = xh · Mt^T-contraction  (fp16 out) --------
// 256x128 tile, 512 thr / 8 waves (4x2), BK=32, 3-buffer counted schedule.
__global__ __launch_bounds__(512, 4) void k_y(
    const h16* __restrict__ xh, const h16* __restrict__ Mt,
    h16* __restrict__ y) {
  __shared__ alignas(16) h16 As[3][256 * 32];   // 48 KB
  __shared__ alignas(16) h16 Bs[3][128 * 32];   // 24 KB
  int tid = threadIdx.x;
  int w = tid >> 6, lane = tid & 63;
  int wrow = w >> 1, wcol = w & 1;
  int g = lane >> 4, l15 = lane & 15;
  int swz = (l15 >> 1) & 3;

  // XCD swizzle: 512 blocks; XCD x owns 8 m-tiles x 8 n-tiles, n fastest.
  int idx = (blockIdx.x & 7) * 64 + (blockIdx.x >> 3);
  int m0 = (idx >> 3) * 256, n0 = (idx & 7) * 128;

  const h16* abase0 = xh + (size_t)(m0 + (2 * w) * 16) * D_;
  const h16* abase1 = abase0 + (size_t)16 * D_;
  const h16* bbase  = Mt + (size_t)(n0 + w * 16) * D_;

  f32x4 acc[4][4] = {};

  #define STAGE_Y(ap, bp, k)                                 \
    {                                                        \
      int k0_ = (k) * 32;                                    \
      stage16(abase0 + k0_, D_, (ap) + (2 * w) * 512);       \
      stage16(abase1 + k0_, D_, (ap) + (2 * w + 1) * 512);   \
      stage16(bbase + k0_, D_, (bp) + w * 512);              \
    }

  h16 *A0 = As[0], *A1 = As[1], *A2 = As[2];
  h16 *B0 = Bs[0], *B1 = Bs[1], *B2 = Bs[2];
  STAGE_Y(A0, B0, 0);
  STAGE_Y(A1, B1, 1);
  for (int k = 0; k < 32; ++k) {
    if (k + 2 < 32) {
      STAGE_Y(A2, B2, k + 2);
      VMCNT(6);
    } else if (k + 1 < 32) {
      VMCNT(3);
    } else {
      VMCNT(0);
    }
    SFENCE();
    SBAR();
    SFENCE();
    f16x8 af[4], bf[4];
    #pragma unroll
    for (int i = 0; i < 4; ++i) {
      af[i] = *(const f16x8*)(A0 + (wrow * 64 + i * 16 + l15) * 32 + (g ^ swz) * 8);
      bf[i] = *(const f16x8*)(B0 + (wcol * 64 + i * 16 + l15) * 32 + (g ^ swz) * 8);
    }
    __builtin_amdgcn_s_setprio(1);
    #pragma unroll
    for (int mi = 0; mi < 4; ++mi)
      #pragma unroll
      for (int ni = 0; ni < 4; ++ni)
        acc[mi][ni] = MFMA16(af[mi], bf[ni], acc[mi][ni]);
    __builtin_amdgcn_s_setprio(0);
    SBAR();
    h16* t;
    t = A0; A0 = A1; A1 = A2; A2 = t;
    t = B0; B0 = B1; B1 = B2; B2 = t;
  }

  #pragma unroll
  for (int ni = 0; ni < 4; ++ni) {
    int n = n0 + wcol * 64 + ni * 16 + l15;
    #pragma unroll
    for (int mi = 0; mi < 4; ++mi) {
      #pragma unroll
      for (int r = 0; r < 4; ++r) {
        int m = m0 + wrow * 64 + mi * 16 + g * 4 + r;
        y[(size_t)m * D_ + n] = (h16)(acc[mi][ni][r]);
      }
    }
  }
}

// -- kernel 5: scores block 128q x 256k = y·xh^T (+c_t), softmax partial -----
// 1024 blocks (2/CU). 3-buffer counted-vmcnt schedule, 3 loads/wave/step.
__global__ __launch_bounds__(512, 4) void k_attn(
    const h16* __restrict__ y, const h16* __restrict__ xh,
    const float* __restrict__ wv, const float* __restrict__ cv,
    float* __restrict__ part) {
  __shared__ alignas(16) h16 Qs[3][128 * 32];   // 24 KB
  __shared__ alignas(16) h16 Ks[3][256 * 32];   // 48 KB
  __shared__ float sm[3][4][128];               // 6 KB
  int tid = threadIdx.x;
  int w = tid >> 6, lane = tid & 63;
  int g = lane >> 4, l15 = lane & 15;
  int swz = (l15 >> 1) & 3;
  int wq = w >> 2, wkc = w & 3;                  // wave: 64q x 64k sub-tile
  int b = blockIdx.x & 7;
  int r = blockIdx.x >> 3;
  int kc = r >> 4;
  int q0 = (r & 15) * 128;
  size_t rbase = (size_t)b * S_;

  const h16* qbase  = y + (rbase + q0 + w * 16) * D_;
  const h16* kbase0 = xh + (rbase + kc * 256 + (2 * w) * 16) * D_;
  const h16* kbase1 = kbase0 + (size_t)16 * D_;

  #define STAGE_ATTN(qp, kp, st)                             \
    {                                                        \
      int k0_ = (st) * 32;                                   \
      stage16(qbase + k0_, D_, (qp) + w * 512);              \
      stage16(kbase0 + k0_, D_, (kp) + (2 * w) * 512);       \
      stage16(kbase1 + k0_, D_, (kp) + (2 * w + 1) * 512);   \
    }

  f32x4 acc[4][4] = {};

  h16 *Q0 = Qs[0], *Q1 = Qs[1], *Q2 = Qs[2];
  h16 *K0 = Ks[0], *K1 = Ks[1], *K2 = Ks[2];
  STAGE_ATTN(Q0, K0, 0);
  STAGE_ATTN(Q1, K1, 1);
  for (int st = 0; st < 32; ++st) {
    if (st + 2 < 32) {
      STAGE_ATTN(Q2, K2, st + 2);
      VMCNT(6);
    } else if (st + 1 < 32) {
      VMCNT(3);
    } else {
      VMCNT(0);
    }
    SFENCE();
    SBAR();
    SFENCE();
    f16x8 qf[4], kf[4];
    #pragma unroll
    for (int i = 0; i < 4; ++i) {
      qf[i] = *(const f16x8*)(Q0 + (wq * 64 + i * 16 + l15) * 32 + (g ^ swz) * 8);
      kf[i] = *(const f16x8*)(K0 + (wkc * 64 + i * 16 + l15) * 32 + (g ^ swz) * 8);
    }
    __builtin_amdgcn_s_setprio(1);
    #pragma unroll
    for (int mi = 0; mi < 4; ++mi)
      #pragma unroll
      for (int ni = 0; ni < 4; ++ni)
        acc[mi][ni] = MFMA16(qf[mi], kf[ni], acc[mi][ni]);
    __builtin_amdgcn_s_setprio(0);
    SBAR();
    h16* t;
    t = Q0; Q0 = Q1; Q1 = Q2; Q2 = t;
    t = K0; K0 = K1; K1 = K2; K2 = t;
  }

  // ---- softmax partial over this block's 256 keys (scores + c_t) ----
  float wvv[4], cvv[4];
  #pragma unroll
  for (int ni = 0; ni < 4; ++ni) {
    size_t t = rbase + kc * 256 + wkc * 64 + ni * 16 + l15;
    wvv[ni] = wv[t];
    cvv[ni] = cv[t];
  }
  #pragma unroll
  for (int mi = 0; mi < 4; ++mi) {
    #pragma unroll
    for (int rr = 0; rr < 4; ++rr) {
      float s0 = acc[mi][0][rr] + cvv[0];
      float s1 = acc[mi][1][rr] + cvv[1];
      float s2 = acc[mi][2][rr] + cvv[2];
      float s3 = acc[mi][3][rr] + cvv[3];
      float v = fmaxf(fmaxf(s0, s1), fmaxf(s2, s3));
      #pragma unroll
      for (int off = 1; off < 16; off <<= 1) v = fmaxf(v, __shfl_xor(v, off, 64));
      float p0 = __expf(s0 - v), p1 = __expf(s1 - v);
      float p2 = __expf(s2 - v), p3 = __expf(s3 - v);
      float pn = p0 * wvv[0] + p1 * wvv[1] + p2 * wvv[2] + p3 * wvv[3];
      float pd = p0 + p1 + p2 + p3;
      #pragma unroll
      for (int off = 1; off < 16; off <<= 1) {
        pn += __shfl_xor(pn, off, 64);
        pd += __shfl_xor(pd, off, 64);
      }
      if (l15 == 0) {
        int row = wq * 64 + mi * 16 + g * 4 + rr;
        sm[0][wkc][row] = v;
        sm[1][wkc][row] = pn;
        sm[2][wkc][row] = pd;
      }
    }
  }
  __syncthreads();
  if (tid < 128) {
    float M = sm[0][0][tid];
    #pragma unroll
    for (int j = 1; j < 4; ++j) M = fmaxf(M, sm[0][j][tid]);
    float N = 0.f, Dn = 0.f;
    #pragma unroll
    for (int j = 0; j < 4; ++j) {
      float e = __expf(sm[0][j][tid] - M);
      N += sm[1][j][tid] * e;
      Dn += sm[2][j][tid] * e;
    }
    size_t row = rbase + q0 + tid;
    part[row * 24 + kc * 3 + 0] = M;
    part[row * 24 + kc * 3 + 1] = N;
    part[row * 24 + kc * 3 + 2] = Dn;
  }
}

// ------------- kernel 6: merge the 8 key-chunk partials ---------------------
__global__ void k_fin(const float* __restrict__ part, const float* __restrict__ bo,
                      float* __restrict__ out) {
  int idx = blockIdx.x * 256 + threadIdx.x;
  if (idx >= B_ * S_) return;
  const float* p = part + (size_t)idx * 24;
  float M = p[0];
  #pragma unroll
  for (int j = 1; j < 8; ++j) M = fmaxf(M, p[j * 3]);
  float N = 0.f, Dn = 0.f;
  #pragma unroll
  for (int j = 0; j < 8; ++j) {
    float e = __expf(p[j * 3] - M);
    N += p[j * 3 + 1] * e;
    Dn += p[j * 3 + 2] * e;
  }
  out[idx] = N / Dn + bo[0];
}

extern "C" void kernel_launch(void* const* d_in, const int* in_sizes, int n_in,
                              void* d_out, int out_size, void* d_ws, size_t ws_size,
                              hipStream_t stream) {
  const float* x  = (const float*)d_in[0];
  const float* Wq = (const float*)d_in[1];
  const float* bq = (const float*)d_in[2];
  const float* Wk = (const float*)d_in[3];
  const float* bk = (const float*)d_in[4];
  const float* Wv = (const float*)d_in[5];
  const float* bv = (const float*)d_in[6];
  const float* Wo = (const float*)d_in[7];
  const float* bo = (const float*)d_in[8];
  float* out = (float*)d_out;
  (void)bk;  // bq·bk and a_s terms cancel in softmax (row-constant)

  char* ws = (char*)d_ws;
  h16*   xh   = (h16*)ws;                                          // 32 MB
  h16*   yb   = (h16*)(ws + (size_t)32 * 1024 * 1024);             // 32 MB
  h16*   Mt   = (h16*)(ws + (size_t)64 * 1024 * 1024);             // 2 MB
  h16*   Wqh  = (h16*)(ws + (size_t)66 * 1024 * 1024);             // 2 MB
  h16*   Wkh  = (h16*)(ws + (size_t)68 * 1024 * 1024);             // 2 MB
  float* wv   = (float*)(ws + (size_t)70 * 1024 * 1024);           // 64 KB
  float* cv   = (float*)(ws + (size_t)70 * 1024 * 1024 + 65536);   // 64 KB
  float* u    = (float*)(ws + (size_t)70 * 1024 * 1024 + 131072);  // 4.1 KB
  float* v2   = (float*)(ws + (size_t)70 * 1024 * 1024 + 139264);  // 4 KB
  float* part = (float*)(ws + (size_t)71 * 1024 * 1024);           // 1.5 MB

  hipLaunchKernelGGL(k_cast, dim3(2048), dim3(256), 0, stream, Wq, Wk, Wqh, Wkh);
  hipLaunchKernelGGL(k_u,    dim3(257),  dim3(256), 0, stream, Wv, Wk, Wo, bq, bv, u, v2);
  hipLaunchKernelGGL(k_xw,   dim3(4096), dim3(256), 0, stream, x, u, v2, xh, wv, cv);
  hipLaunchKernelGGL(k_mt,   dim3(64),   dim3(256), 0, stream, Wkh, Wqh, Mt);
  hipLaunchKernelGGL(k_y,    dim3(512),  dim3(512), 0, stream, xh, Mt, yb);
  hipLaunchKernelGGL(k_attn, dim3(1024), dim3(512), 0, stream, yb, xh, wv, cv, part);
  hipLaunchKernelGGL(k_fin,  dim3(64),   dim3(256), 0, stream, part, bo, out);
}